// Round 1
// baseline (2035.651 us; speedup 1.0000x reference)
//
#include <hip/hip_runtime.h>
#include <math.h>

// Problem constants
constexpr int Nn  = 100000;  // nodes
constexpr int Ee  = 800000;  // edges
constexpr int Bb  = 4096;    // graphs
constexpr int Vv  = 103;     // vocab
constexpr int DIN = 200;     // embedding dim
constexpr int Hh  = 256;     // hidden

__device__ __forceinline__ float sigf(float x){ return 1.f/(1.f+expf(-x)); }

// ---------------- small utility kernels ----------------
__global__ void k_transpose(const float* __restrict__ in, float* __restrict__ out, int R, int C){
  int idx = blockIdx.x*256 + threadIdx.x;
  if (idx >= R*C) return;
  int r = idx / C, c = idx % C;
  out[(size_t)c*R + r] = in[(size_t)r*C + c];
}

__global__ void k_count(const int* __restrict__ dst, int* __restrict__ counts){
  int e = blockIdx.x*256 + threadIdx.x;
  if (e < Ee) atomicAdd(&counts[dst[e]], 1);
}

__global__ void k_dinv(const int* __restrict__ counts, float* __restrict__ dinv){
  int n = blockIdx.x*256 + threadIdx.x;
  if (n < Nn) dinv[n] = rsqrtf((float)(counts[n] + 1));  // +1 self loop, deg>=1
}

// single-block exclusive scan of counts[0..Nn) -> offs[0..Nn]
__global__ void k_scan(const int* __restrict__ counts, int* __restrict__ offs){
  __shared__ int part[1024];
  int tid = threadIdx.x;
  const int chunk = (Nn + 1023)/1024;
  int s = tid*chunk, e2 = min(s+chunk, Nn);
  int sum = 0;
  for (int i=s; i<e2; ++i) sum += counts[i];
  part[tid] = sum; __syncthreads();
  for (int off=1; off<1024; off<<=1){
    int t = (tid>=off) ? part[tid-off] : 0;
    __syncthreads();
    part[tid] += t;
    __syncthreads();
  }
  int run = part[tid] - sum;  // exclusive base
  for (int i=s; i<e2; ++i){ offs[i] = run; run += counts[i]; }
  if (tid == 1023) offs[Nn] = part[1023];
}

__global__ void k_copyi(const int* __restrict__ a, int* __restrict__ b, int n){
  int i = blockIdx.x*256 + threadIdx.x;
  if (i < n) b[i] = a[i];
}

__global__ void k_fill(const int* __restrict__ ei, const float* __restrict__ dinv,
                       int* __restrict__ fptr, int* __restrict__ srcs, float* __restrict__ norms){
  int e = blockIdx.x*256 + threadIdx.x;
  if (e >= Ee) return;
  int s = ei[e], d = ei[Ee + e];
  int pos = atomicAdd(&fptr[d], 1);
  srcs[pos]  = s;
  norms[pos] = dinv[s]*dinv[d];
}

__global__ void k_boffs(const int* __restrict__ batch, int* __restrict__ boffs){
  int b = blockIdx.x*256 + threadIdx.x;
  if (b > Bb) return;
  int lo = 0, hi = Nn;                 // lower_bound: first n with batch[n] >= b
  while (lo < hi){ int mid = (lo+hi)>>1; if (batch[mid] < b) lo = mid+1; else hi = mid; }
  boffs[b] = lo;
}

// ---------------- GCN conv (gather over CSR) ----------------
// layer 0: rows come from the 103x256 WG0 table via embedding index
__global__ void k_conv0(const float* __restrict__ WG0, const int* __restrict__ sto_x,
                        const int* __restrict__ offs, const int* __restrict__ srcs,
                        const float* __restrict__ norms, const float* __restrict__ dinv,
                        const float* __restrict__ bias, float* __restrict__ out){
  int n = blockIdx.x, c = threadIdx.x;
  int row = sto_x[n]; row = (row == 0) ? (Vv-1) : row-1;
  float dn = dinv[n];
  float acc = WG0[row*Hh + c] * dn * dn;
  int s = offs[n], e2 = offs[n+1];
  for (int k=s; k<e2; ++k){
    int sr = srcs[k];
    int r2 = sto_x[sr]; r2 = (r2 == 0) ? (Vv-1) : r2-1;
    acc += WG0[r2*Hh + c] * norms[k];
  }
  acc += bias[c];
  out[(size_t)n*Hh + c] = fmaxf(acc, 0.f);
}

// generic conv: out[n] = act(sum_csr hw[src]*norm + hw[n]*dinv^2 + bias) (* sw[n])
__global__ void k_conv(const float* __restrict__ hw, const int* __restrict__ offs,
                       const int* __restrict__ srcs, const float* __restrict__ norms,
                       const float* __restrict__ dinv, const float* __restrict__ bias,
                       const float* __restrict__ sw, int relu, float* __restrict__ out){
  int n = blockIdx.x, c = threadIdx.x;
  float dn = dinv[n];
  float acc = hw[(size_t)n*Hh + c] * dn * dn;
  int s = offs[n], e2 = offs[n+1];
  for (int k=s; k<e2; ++k)
    acc += hw[(size_t)srcs[k]*Hh + c] * norms[k];
  acc += bias[c];
  if (relu) acc = fmaxf(acc, 0.f);
  if (sw)   acc *= sw[n];
  out[(size_t)n*Hh + c] = acc;
}

// ---------------- tiled fp32 NT GEMM ----------------
// C[m][n] (+)= sum_k A[m*K+k]*Bt[n*K+k] (+bias[n]) (+Dadd[m*Nc+n]); act1 = leaky0.01
__global__ __launch_bounds__(256) void k_gemm_nt(
    const float* __restrict__ A, const float* __restrict__ Bt,
    const float* __restrict__ bias, const float* __restrict__ Dadd,
    float* __restrict__ C, int M, int K, int Nc, int accum, int act)
{
  __shared__ float As[64][20];
  __shared__ float Bs[64][20];
  int tid = threadIdx.x;
  int rbase = blockIdx.y*64, cbase = blockIdx.x*64;
  int ty = tid>>4, tx = tid&15;
  int lr = tid>>2, lq = tid&3;
  float acc[4][4] = {};
  for (int k0 = 0; k0 < K; k0 += 16){
    float4 av = make_float4(0,0,0,0), bv = make_float4(0,0,0,0);
    int kk = k0 + lq*4;
    int ar = rbase + lr;
    if (ar < M && kk < K){
      if (kk + 3 < K) av = *reinterpret_cast<const float4*>(A + (size_t)ar*K + kk);
      else { float t0[4] = {0,0,0,0}; for (int i=0; i<4 && kk+i<K; ++i) t0[i] = A[(size_t)ar*K + kk + i];
             av = make_float4(t0[0],t0[1],t0[2],t0[3]); }
    }
    int br = cbase + lr;
    if (br < Nc && kk < K){
      if (kk + 3 < K) bv = *reinterpret_cast<const float4*>(Bt + (size_t)br*K + kk);
      else { float t0[4] = {0,0,0,0}; for (int i=0; i<4 && kk+i<K; ++i) t0[i] = Bt[(size_t)br*K + kk + i];
             bv = make_float4(t0[0],t0[1],t0[2],t0[3]); }
    }
    __syncthreads();
    *reinterpret_cast<float4*>(&As[lr][lq*4]) = av;
    *reinterpret_cast<float4*>(&Bs[lr][lq*4]) = bv;
    __syncthreads();
    #pragma unroll
    for (int kc = 0; kc < 16; kc += 4){
      float4 a4[4], b4[4];
      #pragma unroll
      for (int i=0;i<4;++i) a4[i] = *reinterpret_cast<float4*>(&As[ty*4+i][kc]);
      #pragma unroll
      for (int j=0;j<4;++j) b4[j] = *reinterpret_cast<float4*>(&Bs[tx*4+j][kc]);
      #pragma unroll
      for (int i=0;i<4;++i)
        #pragma unroll
        for (int j=0;j<4;++j)
          acc[i][j] += a4[i].x*b4[j].x + a4[i].y*b4[j].y + a4[i].z*b4[j].z + a4[i].w*b4[j].w;
    }
  }
  #pragma unroll
  for (int i=0;i<4;++i){
    int r = rbase + ty*4 + i;
    if (r >= M) continue;
    #pragma unroll
    for (int j=0;j<4;++j){
      int cc = cbase + tx*4 + j;
      if (cc >= Nc) continue;
      float v = acc[i][j];
      if (accum) v += C[(size_t)r*Nc + cc];
      if (bias)  v += bias[cc];
      if (Dadd)  v += Dadd[(size_t)r*Nc + cc];
      if (act == 1) v = (v > 0.f) ? v : 0.01f*v;
      C[(size_t)r*Nc + cc] = v;
    }
  }
}

// ---------------- pooling / LSTM / head ----------------
__global__ void k_sto(const float* __restrict__ wx, const int* __restrict__ boffs,
                      float* __restrict__ sto){
  int b = blockIdx.x, c = threadIdx.x;
  int s = boffs[b], e2 = boffs[b+1];
  float acc = 0.f;
  for (int n=s; n<e2; ++n) acc += wx[(size_t)n*Hh + c];
  sto[(size_t)b*Hh + c] = acc;
}

__global__ void k_bsum(const float* __restrict__ bih, const float* __restrict__ bhh,
                       float* __restrict__ bsum){
  int g = blockIdx.x*256 + threadIdx.x;
  if (g < 4*Hh) bsum[g] = bih[g] + bhh[g];
}

__global__ void k_lstm(const float* __restrict__ gates, float* __restrict__ cbuf,
                       float* __restrict__ hbuf, float* __restrict__ qstar){
  int idx = blockIdx.x*256 + threadIdx.x;
  if (idx >= Bb*Hh) return;
  int b = idx >> 8, ch = idx & 255;
  const float* g = gates + (size_t)b*4*Hh;
  float ig = sigf(g[ch]);
  float fg = sigf(g[Hh + ch]);
  float gg = tanhf(g[2*Hh + ch]);
  float og = sigf(g[3*Hh + ch]);
  float cn = fg*cbuf[idx] + ig*gg;
  float hn = og*tanhf(cn);
  cbuf[idx] = cn; hbuf[idx] = hn;
  qstar[(size_t)b*2*Hh + ch] = hn;
}

__global__ void k_e(const float* __restrict__ wx, const float* __restrict__ hbuf,
                    const int* __restrict__ batch, float* __restrict__ ebuf){
  int node = blockIdx.x*4 + (threadIdx.x >> 6);
  int lane = threadIdx.x & 63;
  if (node >= Nn) return;
  int b = batch[node];
  const float* w = wx  + (size_t)node*Hh;
  const float* h = hbuf + (size_t)b*Hh;
  float v = 0.f;
  #pragma unroll
  for (int i=0;i<4;++i) v += w[lane + 64*i]*h[lane + 64*i];
  for (int off=32; off; off>>=1) v += __shfl_down(v, off, 64);
  if (lane == 0) ebuf[node] = v;
}

__global__ void k_attn(const float* __restrict__ ebuf, const float* __restrict__ wx,
                       const int* __restrict__ boffs, float* __restrict__ pbuf,
                       float* __restrict__ qstar){
  __shared__ float red[256];
  int b = blockIdx.x, tid = threadIdx.x;
  int s = boffs[b], e2 = boffs[b+1];
  float m = -INFINITY;
  for (int n=s+tid; n<e2; n+=256) m = fmaxf(m, ebuf[n]);
  red[tid] = m; __syncthreads();
  for (int st=128; st>0; st>>=1){ if (tid<st) red[tid] = fmaxf(red[tid], red[tid+st]); __syncthreads(); }
  m = red[0]; __syncthreads();
  float sum = 0.f;
  for (int n=s+tid; n<e2; n+=256){ float p = expf(ebuf[n]-m); pbuf[n] = p; sum += p; }
  red[tid] = sum; __syncthreads();
  for (int st=128; st>0; st>>=1){ if (tid<st) red[tid] += red[tid+st]; __syncthreads(); }
  float inv = 1.f/(red[0] + 1e-16f);
  float racc = 0.f;
  for (int n=s; n<e2; ++n) racc += pbuf[n]*wx[(size_t)n*Hh + tid];
  qstar[(size_t)b*2*Hh + Hh + tid] = racc*inv;
}

__global__ void k_norm(float* __restrict__ mean){
  __shared__ float red[256];
  int b = blockIdx.x, tid = threadIdx.x;
  float v = mean[(size_t)b*Hh + tid];
  red[tid] = v*v; __syncthreads();
  for (int st=128; st>0; st>>=1){ if (tid<st) red[tid] += red[tid+st]; __syncthreads(); }
  float nrm = fmaxf(sqrtf(red[0]), 1e-12f);
  mean[(size_t)b*Hh + tid] = v/nrm;
}

__global__ void k_out(const float* __restrict__ y1, const float* __restrict__ p2W,
                      const float* __restrict__ p2b, float* __restrict__ out){
  __shared__ float red[128];
  int b = blockIdx.x, tid = threadIdx.x;
  float v = y1[(size_t)b*128 + tid]*p2W[tid];
  red[tid] = v; __syncthreads();
  for (int st=64; st>0; st>>=1){ if (tid<st) red[tid] += red[tid+st]; __syncthreads(); }
  if (tid == 0) out[b] = red[0] + p2b[0];
}

// ---------------- launch ----------------
extern "C" void kernel_launch(void* const* d_in, const int* in_sizes, int n_in,
                              void* d_out, int out_size, void* d_ws, size_t ws_size,
                              hipStream_t stream) {
  const float* weight   = (const float*)d_in[0];
  const int*   sto_x    = (const int*)  d_in[1];
  const int*   ei       = (const int*)  d_in[2];
  const float* sto_w    = (const float*)d_in[3];
  const int*   batch    = (const int*)  d_in[4];
  const float* gW0 = (const float*)d_in[5];   const float* gb0 = (const float*)d_in[6];
  const float* gW1 = (const float*)d_in[7];   const float* gb1 = (const float*)d_in[8];
  const float* gW2 = (const float*)d_in[9];   const float* gb2 = (const float*)d_in[10];
  const float* Wih = (const float*)d_in[11];  const float* Whh = (const float*)d_in[12];
  const float* bih = (const float*)d_in[13];  const float* bhh = (const float*)d_in[14];
  const float* mW  = (const float*)d_in[15];  const float* mb  = (const float*)d_in[16];
  const float* p0W = (const float*)d_in[17];  const float* p0b = (const float*)d_in[18];
  const float* p1W = (const float*)d_in[19];  const float* p1b = (const float*)d_in[20];
  const float* p2W = (const float*)d_in[21];  const float* p2b = (const float*)d_in[22];
  float* out = (float*)d_out;

  // workspace carve (256B aligned)
  char* w = (char*)d_ws;
  auto alloc = [&](size_t bytes)->char*{ char* p = w; w += (bytes + 255) & ~size_t(255); return p; };
  float* X     = (float*)alloc((size_t)Nn*Hh*4);
  float* Y     = (float*)alloc((size_t)Nn*Hh*4);
  float* WG0   = (float*)alloc((size_t)Vv*Hh*4);
  float* gW0t  = (float*)alloc((size_t)Hh*DIN*4);
  float* gW1t  = (float*)alloc((size_t)Hh*Hh*4);
  float* gW2t  = (float*)alloc((size_t)Hh*Hh*4);
  int*   counts= (int*)  alloc((size_t)Nn*4);
  int*   offs  = (int*)  alloc((size_t)(Nn+1)*4);
  int*   fptr  = (int*)  alloc((size_t)Nn*4);
  float* dinv  = (float*)alloc((size_t)Nn*4);
  int*   srcs  = (int*)  alloc((size_t)Ee*4);
  float* norms = (float*)alloc((size_t)Ee*4);
  int*   boffs = (int*)  alloc((size_t)(Bb+1)*4);
  float* ebuf  = (float*)alloc((size_t)Nn*4);
  float* pbuf  = (float*)alloc((size_t)Nn*4);
  float* sto   = (float*)alloc((size_t)Bb*Hh*4);
  float* hbuf  = (float*)alloc((size_t)Bb*Hh*4);
  float* cbuf  = (float*)alloc((size_t)Bb*Hh*4);
  float* qstar = (float*)alloc((size_t)Bb*2*Hh*4);
  float* gates = (float*)alloc((size_t)Bb*4*Hh*4);
  float* bsum  = (float*)alloc((size_t)4*Hh*4);
  float* meanb = (float*)alloc((size_t)Bb*Hh*4);
  float* y0    = (float*)alloc((size_t)Bb*128*4);
  float* y1    = (float*)alloc((size_t)Bb*128*4);

  auto gemm = [&](const float* A, const float* Bt, const float* bias, const float* Dadd,
                  float* C, int M, int K, int Nc, int accum, int act){
    dim3 g((Nc+63)/64, (M+63)/64);
    k_gemm_nt<<<g, 256, 0, stream>>>(A, Bt, bias, Dadd, C, M, K, Nc, accum, act);
  };

  // per-launch state init (must be deterministic every call)
  hipMemsetAsync(counts, 0, (size_t)Nn*4, stream);
  hipMemsetAsync(hbuf,  0, (size_t)Bb*Hh*4, stream);
  hipMemsetAsync(cbuf,  0, (size_t)Bb*Hh*4, stream);
  hipMemsetAsync(qstar, 0, (size_t)Bb*2*Hh*4, stream);

  // weight transposes to NT layout
  k_transpose<<<(DIN*Hh+255)/256, 256, 0, stream>>>(gW0, gW0t, DIN, Hh);
  k_transpose<<<(Hh*Hh+255)/256, 256, 0, stream>>>(gW1, gW1t, Hh, Hh);
  k_transpose<<<(Hh*Hh+255)/256, 256, 0, stream>>>(gW2, gW2t, Hh, Hh);

  // graph structure
  k_count<<<(Ee+255)/256, 256, 0, stream>>>(ei + Ee, counts);
  k_dinv<<<(Nn+255)/256, 256, 0, stream>>>(counts, dinv);
  k_scan<<<1, 1024, 0, stream>>>(counts, offs);
  k_copyi<<<(Nn+255)/256, 256, 0, stream>>>(offs, fptr, Nn);
  k_fill<<<(Ee+255)/256, 256, 0, stream>>>(ei, dinv, fptr, srcs, norms);
  k_boffs<<<(Bb+256)/256, 256, 0, stream>>>(batch, boffs);

  // WG0 = weight @ gW0 (103x256) ; GCN layers
  gemm(weight, gW0t, nullptr, nullptr, WG0, Vv, DIN, Hh, 0, 0);
  k_conv0<<<Nn, Hh, 0, stream>>>(WG0, sto_x, offs, srcs, norms, dinv, gb0, X);
  gemm(X, gW1t, nullptr, nullptr, Y, Nn, Hh, Hh, 0, 0);
  k_conv<<<Nn, Hh, 0, stream>>>(Y, offs, srcs, norms, dinv, gb1, nullptr, 1, X);
  gemm(X, gW2t, nullptr, nullptr, Y, Nn, Hh, Hh, 0, 0);
  k_conv<<<Nn, Hh, 0, stream>>>(Y, offs, srcs, norms, dinv, gb2, sto_w, 0, X);  // X = wx

  // graph sums
  k_sto<<<Bb, Hh, 0, stream>>>(X, boffs, sto);
  k_bsum<<<(4*Hh+255)/256, 256, 0, stream>>>(bih, bhh, bsum);

  // Set2Set (2 steps)
  for (int t = 0; t < 2; ++t){
    gemm(qstar, Wih, bsum, nullptr, gates, Bb, 2*Hh, 4*Hh, 0, 0);
    gemm(hbuf,  Whh, nullptr, nullptr, gates, Bb, Hh, 4*Hh, 1, 0);
    k_lstm<<<(Bb*Hh+255)/256, 256, 0, stream>>>(gates, cbuf, hbuf, qstar);
    k_e<<<(Nn+3)/4, 256, 0, stream>>>(X, hbuf, batch, ebuf);
    k_attn<<<Bb, Hh, 0, stream>>>(ebuf, X, boffs, pbuf, qstar);
  }

  // head
  gemm(qstar, mW, mb, sto, meanb, Bb, 2*Hh, Hh, 0, 0);
  k_norm<<<Bb, Hh, 0, stream>>>(meanb);
  gemm(meanb, p0W, p0b, nullptr, y0, Bb, Hh, 128, 0, 1);
  gemm(y0, p1W, p1b, nullptr, y1, Bb, 128, 128, 0, 1);
  k_out<<<Bb, 128, 0, stream>>>(y1, p2W, p2b, out);
}

// Round 2
// 1317.674 us; speedup vs baseline: 1.5449x; 1.5449x over previous
//
#include <hip/hip_runtime.h>
#include <math.h>

// Problem constants
constexpr int Nn  = 100000;  // nodes
constexpr int Ee  = 800000;  // edges
constexpr int Bb  = 4096;    // graphs
constexpr int Vv  = 103;     // vocab
constexpr int DIN = 200;     // embedding dim
constexpr int Hh  = 256;     // hidden

using short8 = __attribute__((ext_vector_type(8))) short;
using f32x4  = __attribute__((ext_vector_type(4))) float;

__device__ __forceinline__ float sigf(float x){ return 1.f/(1.f+expf(-x)); }

// round-to-nearest-even float -> bf16 (as ushort)
__device__ __forceinline__ unsigned short f2bf(float f){
  unsigned int u = __float_as_uint(f);
  u += 0x7FFFu + ((u >> 16) & 1u);
  return (unsigned short)(u >> 16);
}

// ---------------- small utility kernels ----------------
__global__ void k_transpose(const float* __restrict__ in, float* __restrict__ out, int R, int C){
  int idx = blockIdx.x*256 + threadIdx.x;
  if (idx >= R*C) return;
  int r = idx / C, c = idx % C;
  out[(size_t)c*R + r] = in[(size_t)r*C + c];
}

__global__ void k_transpose_b(const float* __restrict__ in, unsigned short* __restrict__ out, int R, int C){
  int idx = blockIdx.x*256 + threadIdx.x;
  if (idx >= R*C) return;
  int r = idx / C, c = idx % C;
  out[(size_t)c*R + r] = f2bf(in[(size_t)r*C + c]);
}

__global__ void k_castb(const float* __restrict__ in, unsigned short* __restrict__ out, int n){
  int i = blockIdx.x*256 + threadIdx.x;
  if (i < n) out[i] = f2bf(in[i]);
}

__global__ void k_count(const int* __restrict__ dst, int* __restrict__ counts){
  int e = blockIdx.x*256 + threadIdx.x;
  if (e < Ee) atomicAdd(&counts[dst[e]], 1);
}

__global__ void k_dinv(const int* __restrict__ counts, float* __restrict__ dinv){
  int n = blockIdx.x*256 + threadIdx.x;
  if (n < Nn) dinv[n] = rsqrtf((float)(counts[n] + 1));  // +1 self loop
}

// single-block exclusive scan of counts[0..Nn) -> offs[0..Nn]
__global__ void k_scan(const int* __restrict__ counts, int* __restrict__ offs){
  __shared__ int part[1024];
  int tid = threadIdx.x;
  const int chunk = (Nn + 1023)/1024;
  int s = tid*chunk, e2 = min(s+chunk, Nn);
  int sum = 0;
  for (int i=s; i<e2; ++i) sum += counts[i];
  part[tid] = sum; __syncthreads();
  for (int off=1; off<1024; off<<=1){
    int t = (tid>=off) ? part[tid-off] : 0;
    __syncthreads();
    part[tid] += t;
    __syncthreads();
  }
  int run = part[tid] - sum;  // exclusive base
  for (int i=s; i<e2; ++i){ offs[i] = run; run += counts[i]; }
  if (tid == 1023) offs[Nn] = part[1023];
}

__global__ void k_copyi(const int* __restrict__ a, int* __restrict__ b, int n){
  int i = blockIdx.x*256 + threadIdx.x;
  if (i < n) b[i] = a[i];
}

__global__ void k_fill(const int* __restrict__ ei, const float* __restrict__ dinv,
                       int* __restrict__ fptr, int* __restrict__ srcs, float* __restrict__ norms){
  int e = blockIdx.x*256 + threadIdx.x;
  if (e >= Ee) return;
  int s = ei[e], d = ei[Ee + e];
  int pos = atomicAdd(&fptr[d], 1);
  srcs[pos]  = s;
  norms[pos] = dinv[s]*dinv[d];
}

__global__ void k_boffs(const int* __restrict__ batch, int* __restrict__ boffs){
  int b = blockIdx.x*256 + threadIdx.x;
  if (b > Bb) return;
  int lo = 0, hi = Nn;
  while (lo < hi){ int mid = (lo+hi)>>1; if (batch[mid] < b) lo = mid+1; else hi = mid; }
  boffs[b] = lo;
}

// ---------------- GCN conv (gather over CSR) ----------------
// layer 0: rows from the 103x256 WG0 table via embedding index; writes bf16
__global__ void k_conv0(const float* __restrict__ WG0, const int* __restrict__ sto_x,
                        const int* __restrict__ offs, const int* __restrict__ srcs,
                        const float* __restrict__ norms, const float* __restrict__ dinv,
                        const float* __restrict__ bias, unsigned short* __restrict__ outb){
  int n = blockIdx.x, c = threadIdx.x;
  int row = sto_x[n]; row = (row == 0) ? (Vv-1) : row-1;
  float dn = dinv[n];
  float acc = WG0[row*Hh + c] * dn * dn;
  int s = offs[n], e2 = offs[n+1];
  for (int k=s; k<e2; ++k){
    int sr = srcs[k];
    int r2 = sto_x[sr]; r2 = (r2 == 0) ? (Vv-1) : r2-1;
    acc += WG0[r2*Hh + c] * norms[k];
  }
  acc += bias[c];
  outb[(size_t)n*Hh + c] = f2bf(fmaxf(acc, 0.f));
}

// generic conv: v = sum_csr hw[src]*norm + hw[n]*dinv^2 + bias; optional relu, sw scale;
// writes fp32 (outf) and/or bf16 (outb)
__global__ void k_conv(const float* __restrict__ hw, const int* __restrict__ offs,
                       const int* __restrict__ srcs, const float* __restrict__ norms,
                       const float* __restrict__ dinv, const float* __restrict__ bias,
                       const float* __restrict__ sw, int relu,
                       float* __restrict__ outf, unsigned short* __restrict__ outb){
  int n = blockIdx.x, c = threadIdx.x;
  float dn = dinv[n];
  float acc = hw[(size_t)n*Hh + c] * dn * dn;
  int s = offs[n], e2 = offs[n+1];
  for (int k=s; k<e2; ++k)
    acc += hw[(size_t)srcs[k]*Hh + c] * norms[k];
  acc += bias[c];
  if (relu) acc = fmaxf(acc, 0.f);
  if (sw)   acc *= sw[n];
  if (outf) outf[(size_t)n*Hh + c] = acc;
  if (outb) outb[(size_t)n*Hh + c] = f2bf(acc);
}

// ---------------- bf16 MFMA NT GEMM ----------------
// C[m][n] (+)= sum_k A[m*K+k]*Bt[n*K+k] (+bias[n]); A,Bt bf16; C fp32.
// Tile 128(M) x 64(N), BK=32. 4 waves, each 32 rows x 64 cols.
// Requires: Nc % 64 == 0, K % 32 == 0.
__global__ __launch_bounds__(256) void k_gemm_bf16(
    const unsigned short* __restrict__ A, const unsigned short* __restrict__ Bt,
    const float* __restrict__ bias, float* __restrict__ C,
    int M, int K, int Nc, int accum)
{
  __shared__ unsigned short Al[128][40];  // 80B row stride (16B-aligned)
  __shared__ unsigned short Bl[64][40];
  int tid = threadIdx.x;
  int w = tid >> 6, lane = tid & 63;
  int l16 = lane & 15, kh = lane >> 4;          // kh in 0..3
  int rbase = blockIdx.y*128, cbase = blockIdx.x*64;
  int sr = tid >> 2, sb = tid & 3;              // staging: row, 16B block

  f32x4 acc0[4] = {}, acc1[4] = {};

  for (int k0 = 0; k0 < K; k0 += 32){
    int kk = k0 + sb*8;
    uint4 av0 = make_uint4(0,0,0,0), av1 = make_uint4(0,0,0,0);
    int ar0 = rbase + sr, ar1 = rbase + sr + 64;
    if (ar0 < M) av0 = *reinterpret_cast<const uint4*>(A + (size_t)ar0*K + kk);
    if (ar1 < M) av1 = *reinterpret_cast<const uint4*>(A + (size_t)ar1*K + kk);
    uint4 bv = *reinterpret_cast<const uint4*>(Bt + (size_t)(cbase + sr)*K + kk);
    __syncthreads();
    *reinterpret_cast<uint4*>(&Al[sr][sb*8])      = av0;
    *reinterpret_cast<uint4*>(&Al[sr+64][sb*8])   = av1;
    *reinterpret_cast<uint4*>(&Bl[sr][sb*8])      = bv;
    __syncthreads();

    short8 a0 = *reinterpret_cast<const short8*>(&Al[w*32 + l16][kh*8]);
    short8 a1 = *reinterpret_cast<const short8*>(&Al[w*32 + 16 + l16][kh*8]);
    #pragma unroll
    for (int j = 0; j < 4; ++j){
      short8 b = *reinterpret_cast<const short8*>(&Bl[j*16 + l16][kh*8]);
      acc0[j] = __builtin_amdgcn_mfma_f32_16x16x32_bf16(a0, b, acc0[j], 0, 0, 0);
      acc1[j] = __builtin_amdgcn_mfma_f32_16x16x32_bf16(a1, b, acc1[j], 0, 0, 0);
    }
  }

  #pragma unroll
  for (int j = 0; j < 4; ++j){
    int col = cbase + j*16 + l16;
    float bv = bias ? bias[col] : 0.f;
    #pragma unroll
    for (int i = 0; i < 4; ++i){
      int row0 = rbase + w*32 + kh*4 + i;
      int row1 = row0 + 16;
      if (row0 < M){
        float v = acc0[j][i] + bv;
        if (accum) v += C[(size_t)row0*Nc + col];
        C[(size_t)row0*Nc + col] = v;
      }
      if (row1 < M){
        float v = acc1[j][i] + bv;
        if (accum) v += C[(size_t)row1*Nc + col];
        C[(size_t)row1*Nc + col] = v;
      }
    }
  }
}

// ---------------- tiled fp32 NT GEMM (small head GEMMs + WG0) ----------------
__global__ __launch_bounds__(256) void k_gemm_nt(
    const float* __restrict__ A, const float* __restrict__ Bt,
    const float* __restrict__ bias, const float* __restrict__ Dadd,
    float* __restrict__ C, int M, int K, int Nc, int accum, int act)
{
  __shared__ float As[64][20];
  __shared__ float Bs[64][20];
  int tid = threadIdx.x;
  int rbase = blockIdx.y*64, cbase = blockIdx.x*64;
  int ty = tid>>4, tx = tid&15;
  int lr = tid>>2, lq = tid&3;
  float acc[4][4] = {};
  for (int k0 = 0; k0 < K; k0 += 16){
    float4 av = make_float4(0,0,0,0), bv = make_float4(0,0,0,0);
    int kk = k0 + lq*4;
    int ar = rbase + lr;
    if (ar < M && kk < K){
      if (kk + 3 < K) av = *reinterpret_cast<const float4*>(A + (size_t)ar*K + kk);
      else { float t0[4] = {0,0,0,0}; for (int i=0; i<4 && kk+i<K; ++i) t0[i] = A[(size_t)ar*K + kk + i];
             av = make_float4(t0[0],t0[1],t0[2],t0[3]); }
    }
    int br = cbase + lr;
    if (br < Nc && kk < K){
      if (kk + 3 < K) bv = *reinterpret_cast<const float4*>(Bt + (size_t)br*K + kk);
      else { float t0[4] = {0,0,0,0}; for (int i=0; i<4 && kk+i<K; ++i) t0[i] = Bt[(size_t)br*K + kk + i];
             bv = make_float4(t0[0],t0[1],t0[2],t0[3]); }
    }
    __syncthreads();
    *reinterpret_cast<float4*>(&As[lr][lq*4]) = av;
    *reinterpret_cast<float4*>(&Bs[lr][lq*4]) = bv;
    __syncthreads();
    #pragma unroll
    for (int kc = 0; kc < 16; kc += 4){
      float4 a4[4], b4[4];
      #pragma unroll
      for (int i=0;i<4;++i) a4[i] = *reinterpret_cast<float4*>(&As[ty*4+i][kc]);
      #pragma unroll
      for (int j=0;j<4;++j) b4[j] = *reinterpret_cast<float4*>(&Bs[tx*4+j][kc]);
      #pragma unroll
      for (int i=0;i<4;++i)
        #pragma unroll
        for (int j=0;j<4;++j)
          acc[i][j] += a4[i].x*b4[j].x + a4[i].y*b4[j].y + a4[i].z*b4[j].z + a4[i].w*b4[j].w;
    }
  }
  #pragma unroll
  for (int i=0;i<4;++i){
    int r = rbase + ty*4 + i;
    if (r >= M) continue;
    #pragma unroll
    for (int j=0;j<4;++j){
      int cc = cbase + tx*4 + j;
      if (cc >= Nc) continue;
      float v = acc[i][j];
      if (accum) v += C[(size_t)r*Nc + cc];
      if (bias)  v += bias[cc];
      if (Dadd)  v += Dadd[(size_t)r*Nc + cc];
      if (act == 1) v = (v > 0.f) ? v : 0.01f*v;
      C[(size_t)r*Nc + cc] = v;
    }
  }
}

// ---------------- pooling / LSTM / head ----------------
__global__ void k_sto(const float* __restrict__ wx, const int* __restrict__ boffs,
                      float* __restrict__ sto){
  int b = blockIdx.x, c = threadIdx.x;
  int s = boffs[b], e2 = boffs[b+1];
  float acc = 0.f;
  for (int n=s; n<e2; ++n) acc += wx[(size_t)n*Hh + c];
  sto[(size_t)b*Hh + c] = acc;
}

__global__ void k_bsum(const float* __restrict__ bih, const float* __restrict__ bhh,
                       float* __restrict__ bsum){
  int g = blockIdx.x*256 + threadIdx.x;
  if (g < 4*Hh) bsum[g] = bih[g] + bhh[g];
}

__global__ void k_lstm(const float* __restrict__ gates, float* __restrict__ cbuf,
                       float* __restrict__ hbuf, float* __restrict__ qstar,
                       unsigned short* __restrict__ hbuf_b, unsigned short* __restrict__ qstar_b){
  int idx = blockIdx.x*256 + threadIdx.x;
  if (idx >= Bb*Hh) return;
  int b = idx >> 8, ch = idx & 255;
  const float* g = gates + (size_t)b*4*Hh;
  float ig = sigf(g[ch]);
  float fg = sigf(g[Hh + ch]);
  float gg = tanhf(g[2*Hh + ch]);
  float og = sigf(g[3*Hh + ch]);
  float cn = fg*cbuf[idx] + ig*gg;
  float hn = og*tanhf(cn);
  cbuf[idx] = cn; hbuf[idx] = hn;
  hbuf_b[idx] = f2bf(hn);
  qstar[(size_t)b*2*Hh + ch] = hn;
  qstar_b[(size_t)b*2*Hh + ch] = f2bf(hn);
}

__global__ void k_e(const float* __restrict__ wx, const float* __restrict__ hbuf,
                    const int* __restrict__ batch, float* __restrict__ ebuf){
  int node = blockIdx.x*4 + (threadIdx.x >> 6);
  int lane = threadIdx.x & 63;
  if (node >= Nn) return;
  int b = batch[node];
  const float* w = wx  + (size_t)node*Hh;
  const float* h = hbuf + (size_t)b*Hh;
  float v = 0.f;
  #pragma unroll
  for (int i=0;i<4;++i) v += w[lane + 64*i]*h[lane + 64*i];
  for (int off=32; off; off>>=1) v += __shfl_down(v, off, 64);
  if (lane == 0) ebuf[node] = v;
}

__global__ void k_attn(const float* __restrict__ ebuf, const float* __restrict__ wx,
                       const int* __restrict__ boffs, float* __restrict__ pbuf,
                       float* __restrict__ qstar, unsigned short* __restrict__ qstar_b){
  __shared__ float red[256];
  int b = blockIdx.x, tid = threadIdx.x;
  int s = boffs[b], e2 = boffs[b+1];
  float m = -INFINITY;
  for (int n=s+tid; n<e2; n+=256) m = fmaxf(m, ebuf[n]);
  red[tid] = m; __syncthreads();
  for (int st=128; st>0; st>>=1){ if (tid<st) red[tid] = fmaxf(red[tid], red[tid+st]); __syncthreads(); }
  m = red[0]; __syncthreads();
  float sum = 0.f;
  for (int n=s+tid; n<e2; n+=256){ float p = expf(ebuf[n]-m); pbuf[n] = p; sum += p; }
  red[tid] = sum; __syncthreads();
  for (int st=128; st>0; st>>=1){ if (tid<st) red[tid] += red[tid+st]; __syncthreads(); }
  float inv = 1.f/(red[0] + 1e-16f);
  float racc = 0.f;
  for (int n=s; n<e2; ++n) racc += pbuf[n]*wx[(size_t)n*Hh + tid];
  float r = racc*inv;
  qstar[(size_t)b*2*Hh + Hh + tid] = r;
  qstar_b[(size_t)b*2*Hh + Hh + tid] = f2bf(r);
}

__global__ void k_norm(float* __restrict__ mean){
  __shared__ float red[256];
  int b = blockIdx.x, tid = threadIdx.x;
  float v = mean[(size_t)b*Hh + tid];
  red[tid] = v*v; __syncthreads();
  for (int st=128; st>0; st>>=1){ if (tid<st) red[tid] += red[tid+st]; __syncthreads(); }
  float nrm = fmaxf(sqrtf(red[0]), 1e-12f);
  mean[(size_t)b*Hh + tid] = v/nrm;
}

__global__ void k_out(const float* __restrict__ y1, const float* __restrict__ p2W,
                      const float* __restrict__ p2b, float* __restrict__ out){
  __shared__ float red[128];
  int b = blockIdx.x, tid = threadIdx.x;
  float v = y1[(size_t)b*128 + tid]*p2W[tid];
  red[tid] = v; __syncthreads();
  for (int st=64; st>0; st>>=1){ if (tid<st) red[tid] += red[tid+st]; __syncthreads(); }
  if (tid == 0) out[b] = red[0] + p2b[0];
}

// ---------------- launch ----------------
extern "C" void kernel_launch(void* const* d_in, const int* in_sizes, int n_in,
                              void* d_out, int out_size, void* d_ws, size_t ws_size,
                              hipStream_t stream) {
  const float* weight   = (const float*)d_in[0];
  const int*   sto_x    = (const int*)  d_in[1];
  const int*   ei       = (const int*)  d_in[2];
  const float* sto_w    = (const float*)d_in[3];
  const int*   batch    = (const int*)  d_in[4];
  const float* gW0 = (const float*)d_in[5];   const float* gb0 = (const float*)d_in[6];
  const float* gW1 = (const float*)d_in[7];   const float* gb1 = (const float*)d_in[8];
  const float* gW2 = (const float*)d_in[9];   const float* gb2 = (const float*)d_in[10];
  const float* Wih = (const float*)d_in[11];  const float* Whh = (const float*)d_in[12];
  const float* bih = (const float*)d_in[13];  const float* bhh = (const float*)d_in[14];
  const float* mW  = (const float*)d_in[15];  const float* mb  = (const float*)d_in[16];
  const float* p0W = (const float*)d_in[17];  const float* p0b = (const float*)d_in[18];
  const float* p1W = (const float*)d_in[19];  const float* p1b = (const float*)d_in[20];
  const float* p2W = (const float*)d_in[21];  const float* p2b = (const float*)d_in[22];
  float* out = (float*)d_out;

  // workspace carve (256B aligned)
  char* w = (char*)d_ws;
  auto alloc = [&](size_t bytes)->char*{ char* p = w; w += (bytes + 255) & ~size_t(255); return p; };
  float* X     = (float*)alloc((size_t)Nn*Hh*4);   // fp32 wx (final); first 1/2 aliased as bf16 X
  float* Y     = (float*)alloc((size_t)Nn*Hh*4);
  float* WG0   = (float*)alloc((size_t)Vv*Hh*4);
  float* gW0t  = (float*)alloc((size_t)Hh*DIN*4);
  unsigned short* gW1tb = (unsigned short*)alloc((size_t)Hh*Hh*2);
  unsigned short* gW2tb = (unsigned short*)alloc((size_t)Hh*Hh*2);
  unsigned short* Wihb  = (unsigned short*)alloc((size_t)4*Hh*2*Hh*2);
  unsigned short* Whhb  = (unsigned short*)alloc((size_t)4*Hh*Hh*2);
  int*   counts= (int*)  alloc((size_t)Nn*4);
  int*   offs  = (int*)  alloc((size_t)(Nn+1)*4);
  int*   fptr  = (int*)  alloc((size_t)Nn*4);
  float* dinv  = (float*)alloc((size_t)Nn*4);
  int*   srcs  = (int*)  alloc((size_t)Ee*4);
  float* norms = (float*)alloc((size_t)Ee*4);
  int*   boffs = (int*)  alloc((size_t)(Bb+1)*4);
  float* ebuf  = (float*)alloc((size_t)Nn*4);
  float* pbuf  = (float*)alloc((size_t)Nn*4);
  float* sto   = (float*)alloc((size_t)Bb*Hh*4);
  float* hbuf  = (float*)alloc((size_t)Bb*Hh*4);
  float* cbuf  = (float*)alloc((size_t)Bb*Hh*4);
  float* qstar = (float*)alloc((size_t)Bb*2*Hh*4);
  unsigned short* hbufb  = (unsigned short*)alloc((size_t)Bb*Hh*2);
  unsigned short* qstarb = (unsigned short*)alloc((size_t)Bb*2*Hh*2);
  float* gates = (float*)alloc((size_t)Bb*4*Hh*4);
  float* bsum  = (float*)alloc((size_t)4*Hh*4);
  float* meanb = (float*)alloc((size_t)Bb*Hh*4);
  float* y0    = (float*)alloc((size_t)Bb*128*4);
  float* y1    = (float*)alloc((size_t)Bb*128*4);

  // bf16 node activations alias into X's storage (Nn*Hh*2 bytes <= Nn*Hh*4)
  unsigned short* Xb = (unsigned short*)X;

  auto gemm = [&](const float* A, const float* Bt, const float* bias, const float* Dadd,
                  float* C, int M, int K, int Nc, int accum, int act){
    dim3 g((Nc+63)/64, (M+63)/64);
    k_gemm_nt<<<g, 256, 0, stream>>>(A, Bt, bias, Dadd, C, M, K, Nc, accum, act);
  };
  auto gemmb = [&](const unsigned short* A, const unsigned short* Bt, const float* bias,
                   float* C, int M, int K, int Nc, int accum){
    dim3 g(Nc/64, (M+127)/128);
    k_gemm_bf16<<<g, 256, 0, stream>>>(A, Bt, bias, C, M, K, Nc, accum);
  };

  // per-launch state init (deterministic every call)
  hipMemsetAsync(counts, 0, (size_t)Nn*4, stream);
  hipMemsetAsync(hbuf,  0, (size_t)Bb*Hh*4, stream);
  hipMemsetAsync(cbuf,  0, (size_t)Bb*Hh*4, stream);
  hipMemsetAsync(qstar, 0, (size_t)Bb*2*Hh*4, stream);
  hipMemsetAsync(hbufb, 0, (size_t)Bb*Hh*2, stream);
  hipMemsetAsync(qstarb,0, (size_t)Bb*2*Hh*2, stream);

  // weight prep
  k_transpose<<<(DIN*Hh+255)/256, 256, 0, stream>>>(gW0, gW0t, DIN, Hh);
  k_transpose_b<<<(Hh*Hh+255)/256, 256, 0, stream>>>(gW1, gW1tb, Hh, Hh);
  k_transpose_b<<<(Hh*Hh+255)/256, 256, 0, stream>>>(gW2, gW2tb, Hh, Hh);
  k_castb<<<(4*Hh*2*Hh+255)/256, 256, 0, stream>>>(Wih, Wihb, 4*Hh*2*Hh);
  k_castb<<<(4*Hh*Hh+255)/256, 256, 0, stream>>>(Whh, Whhb, 4*Hh*Hh);

  // graph structure
  k_count<<<(Ee+255)/256, 256, 0, stream>>>(ei + Ee, counts);
  k_dinv<<<(Nn+255)/256, 256, 0, stream>>>(counts, dinv);
  k_scan<<<1, 1024, 0, stream>>>(counts, offs);
  k_copyi<<<(Nn+255)/256, 256, 0, stream>>>(offs, fptr, Nn);
  k_fill<<<(Ee+255)/256, 256, 0, stream>>>(ei, dinv, fptr, srcs, norms);
  k_boffs<<<(Bb+256)/256, 256, 0, stream>>>(batch, boffs);

  // WG0 = weight @ gW0 (103x256, fp32); GCN layers with bf16 MFMA GEMMs
  gemm(weight, gW0t, nullptr, nullptr, WG0, Vv, DIN, Hh, 0, 0);
  k_conv0<<<Nn, Hh, 0, stream>>>(WG0, sto_x, offs, srcs, norms, dinv, gb0, Xb);
  gemmb(Xb, gW1tb, nullptr, Y, Nn, Hh, Hh, 0);
  k_conv<<<Nn, Hh, 0, stream>>>(Y, offs, srcs, norms, dinv, gb1, nullptr, 1, nullptr, Xb);
  gemmb(Xb, gW2tb, nullptr, Y, Nn, Hh, Hh, 0);
  k_conv<<<Nn, Hh, 0, stream>>>(Y, offs, srcs, norms, dinv, gb2, sto_w, 0, X, nullptr); // X = wx fp32

  // graph sums
  k_sto<<<Bb, Hh, 0, stream>>>(X, boffs, sto);
  k_bsum<<<(4*Hh+255)/256, 256, 0, stream>>>(bih, bhh, bsum);

  // Set2Set (2 steps), gate GEMMs in bf16
  for (int t = 0; t < 2; ++t){
    gemmb(qstarb, Wihb, bsum, gates, Bb, 2*Hh, 4*Hh, 0);
    gemmb(hbufb,  Whhb, nullptr, gates, Bb, Hh, 4*Hh, 1);
    k_lstm<<<(Bb*Hh+255)/256, 256, 0, stream>>>(gates, cbuf, hbuf, qstar, hbufb, qstarb);
    k_e<<<(Nn+3)/4, 256, 0, stream>>>(X, hbuf, batch, ebuf);
    k_attn<<<Bb, Hh, 0, stream>>>(ebuf, X, boffs, pbuf, qstar, qstarb);
  }

  // head (fp32 for accuracy; cheap)
  gemm(qstar, mW, mb, sto, meanb, Bb, 2*Hh, Hh, 0, 0);
  k_norm<<<Bb, Hh, 0, stream>>>(meanb);
  gemm(meanb, p0W, p0b, nullptr, y0, Bb, Hh, 128, 0, 1);
  gemm(y0, p1W, p1b, nullptr, y1, Bb, 128, 128, 0, 1);
  k_out<<<Bb, 128, 0, stream>>>(y1, p2W, p2b, out);
}

// Round 3
// 1234.451 us; speedup vs baseline: 1.6490x; 1.0674x over previous
//
#include <hip/hip_runtime.h>
#include <math.h>

// Problem constants
constexpr int Nn  = 100000;  // nodes
constexpr int Ee  = 800000;  // edges
constexpr int Bb  = 4096;    // graphs
constexpr int Vv  = 103;     // vocab
constexpr int DIN = 200;     // embedding dim
constexpr int Hh  = 256;     // hidden

using short8 = __attribute__((ext_vector_type(8))) short;
using f32x4  = __attribute__((ext_vector_type(4))) float;

__device__ __forceinline__ float sigf(float x){ return 1.f/(1.f+expf(-x)); }

// round-to-nearest-even float -> bf16 (as ushort)
__device__ __forceinline__ unsigned short f2bf(float f){
  unsigned int u = __float_as_uint(f);
  u += 0x7FFFu + ((u >> 16) & 1u);
  return (unsigned short)(u >> 16);
}
__device__ __forceinline__ float bf2f(unsigned short u){
  return __uint_as_float(((unsigned int)u) << 16);
}

// ---------------- small utility kernels ----------------
__global__ void k_transpose(const float* __restrict__ in, float* __restrict__ out, int R, int C){
  int idx = blockIdx.x*256 + threadIdx.x;
  if (idx >= R*C) return;
  int r = idx / C, c = idx % C;
  out[(size_t)c*R + r] = in[(size_t)r*C + c];
}

__global__ void k_transpose_b(const float* __restrict__ in, unsigned short* __restrict__ out, int R, int C){
  int idx = blockIdx.x*256 + threadIdx.x;
  if (idx >= R*C) return;
  int r = idx / C, c = idx % C;
  out[(size_t)c*R + r] = f2bf(in[(size_t)r*C + c]);
}

__global__ void k_castb(const float* __restrict__ in, unsigned short* __restrict__ out, int n){
  int i = blockIdx.x*256 + threadIdx.x;
  if (i < n) out[i] = f2bf(in[i]);
}

// pack [Wih | Whh] -> bf16 [1024][768]
__global__ void k_packW(const float* __restrict__ Wih, const float* __restrict__ Whh,
                        unsigned short* __restrict__ Wp){
  int i = blockIdx.x*256 + threadIdx.x;
  if (i >= 4*Hh*3*Hh) return;
  int g = i / (3*Hh), j = i % (3*Hh);
  float v = (j < 2*Hh) ? Wih[(size_t)g*2*Hh + j] : Whh[(size_t)g*Hh + (j - 2*Hh)];
  Wp[i] = f2bf(v);
}

__global__ void k_count(const int* __restrict__ dst, int* __restrict__ counts){
  int e = blockIdx.x*256 + threadIdx.x;
  if (e < Ee) atomicAdd(&counts[dst[e]], 1);
}

__global__ void k_dinv(const int* __restrict__ counts, float* __restrict__ dinv){
  int n = blockIdx.x*256 + threadIdx.x;
  if (n < Nn) dinv[n] = rsqrtf((float)(counts[n] + 1));  // +1 self loop
}

// single-block exclusive scan of counts[0..Nn) -> offs[0..Nn]
__global__ void k_scan(const int* __restrict__ counts, int* __restrict__ offs){
  __shared__ int part[1024];
  int tid = threadIdx.x;
  const int chunk = (Nn + 1023)/1024;
  int s = tid*chunk, e2 = min(s+chunk, Nn);
  int sum = 0;
  for (int i=s; i<e2; ++i) sum += counts[i];
  part[tid] = sum; __syncthreads();
  for (int off=1; off<1024; off<<=1){
    int t = (tid>=off) ? part[tid-off] : 0;
    __syncthreads();
    part[tid] += t;
    __syncthreads();
  }
  int run = part[tid] - sum;  // exclusive base
  for (int i=s; i<e2; ++i){ offs[i] = run; run += counts[i]; }
  if (tid == 1023) offs[Nn] = part[1023];
}

__global__ void k_copyi(const int* __restrict__ a, int* __restrict__ b, int n){
  int i = blockIdx.x*256 + threadIdx.x;
  if (i < n) b[i] = a[i];
}

__global__ void k_fill(const int* __restrict__ ei, const float* __restrict__ dinv,
                       int* __restrict__ fptr, int* __restrict__ srcs, float* __restrict__ norms){
  int e = blockIdx.x*256 + threadIdx.x;
  if (e >= Ee) return;
  int s = ei[e], d = ei[Ee + e];
  int pos = atomicAdd(&fptr[d], 1);
  srcs[pos]  = s;
  norms[pos] = dinv[s]*dinv[d];
}

__global__ void k_boffs(const int* __restrict__ batch, int* __restrict__ boffs){
  int b = blockIdx.x*256 + threadIdx.x;
  if (b > Bb) return;
  int lo = 0, hi = Nn;
  while (lo < hi){ int mid = (lo+hi)>>1; if (batch[mid] < b) lo = mid+1; else hi = mid; }
  boffs[b] = lo;
}

// ---------------- GCN layer 0: gather from bf16 WG0 table ----------------
__global__ void k_conv0(const unsigned short* __restrict__ WG0b, const int* __restrict__ sto_x,
                        const int* __restrict__ offs, const int* __restrict__ srcs,
                        const float* __restrict__ norms, const float* __restrict__ dinv,
                        const float* __restrict__ bias, unsigned short* __restrict__ outb){
  int n = blockIdx.x, c = threadIdx.x;
  int row = sto_x[n]; row = (row == 0) ? (Vv-1) : row-1;
  float dn = dinv[n];
  float acc = bf2f(WG0b[row*Hh + c]) * dn * dn;
  int s = offs[n], e2 = offs[n+1];
  for (int k=s; k<e2; ++k){
    int sr = srcs[k];
    int r2 = sto_x[sr]; r2 = (r2 == 0) ? (Vv-1) : r2-1;
    acc += bf2f(WG0b[r2*Hh + c]) * norms[k];
  }
  acc += bias[c];
  outb[(size_t)n*Hh + c] = f2bf(fmaxf(acc, 0.f));
}

// ---------------- GCN aggregate (bf16 gather, bf16 out) ----------------
// T[n] = X[n]*dinv[n]^2 + sum_csr X[src]*norm  (bias/relu applied in GEMM epilogue)
__global__ void k_agg(const unsigned short* __restrict__ Xb, const int* __restrict__ offs,
                      const int* __restrict__ srcs, const float* __restrict__ norms,
                      const float* __restrict__ dinv, unsigned short* __restrict__ T){
  int n = blockIdx.x, c = threadIdx.x;
  float dn = dinv[n];
  float acc = bf2f(Xb[(size_t)n*Hh + c]) * dn * dn;
  int s = offs[n], e2 = offs[n+1];
  for (int k=s; k<e2; ++k)
    acc += bf2f(Xb[(size_t)srcs[k]*Hh + c]) * norms[k];
  T[(size_t)n*Hh + c] = f2bf(acc);
}

// ---------------- bf16 MFMA NT GEMM, 128x128 tile ----------------
// out[m][n] = epi( sum_k A[m*K+k]*Bt[n*K+k] + bias[n] ), epi: *rowscale[m], relu
// writes fp32 (Cf) and/or bf16 (Cb). Requires Nc % 128 == 0, K % 32 == 0.
__global__ __launch_bounds__(256) void k_gemm_bf16(
    const unsigned short* __restrict__ A, const unsigned short* __restrict__ Bt,
    const float* __restrict__ bias, const float* __restrict__ rowscale,
    float* __restrict__ Cf, unsigned short* __restrict__ Cb,
    int M, int K, int Nc, int relu)
{
  __shared__ unsigned short Al[128][40];
  __shared__ unsigned short Bl[128][40];
  int tid = threadIdx.x;
  int w = tid >> 6, lane = tid & 63;
  int wr = (w >> 1)*64, wc = (w & 1)*64;
  int l16 = lane & 15, kh = lane >> 4;
  int rbase = blockIdx.y*128, cbase = blockIdx.x*128;
  int sr = tid >> 2, sb = tid & 3;

  f32x4 acc[4][4] = {};

  for (int k0 = 0; k0 < K; k0 += 32){
    int kk = k0 + sb*8;
    uint4 a0 = make_uint4(0,0,0,0), a1 = make_uint4(0,0,0,0);
    int ar0 = rbase + sr, ar1 = rbase + sr + 64;
    if (ar0 < M) a0 = *reinterpret_cast<const uint4*>(A + (size_t)ar0*K + kk);
    if (ar1 < M) a1 = *reinterpret_cast<const uint4*>(A + (size_t)ar1*K + kk);
    uint4 b0 = *reinterpret_cast<const uint4*>(Bt + (size_t)(cbase + sr)*K + kk);
    uint4 b1 = *reinterpret_cast<const uint4*>(Bt + (size_t)(cbase + sr + 64)*K + kk);
    __syncthreads();
    *reinterpret_cast<uint4*>(&Al[sr][sb*8])    = a0;
    *reinterpret_cast<uint4*>(&Al[sr+64][sb*8]) = a1;
    *reinterpret_cast<uint4*>(&Bl[sr][sb*8])    = b0;
    *reinterpret_cast<uint4*>(&Bl[sr+64][sb*8]) = b1;
    __syncthreads();

    short8 af[4], bfv[4];
    #pragma unroll
    for (int m = 0; m < 4; ++m) af[m] = *reinterpret_cast<const short8*>(&Al[wr + m*16 + l16][kh*8]);
    #pragma unroll
    for (int n2 = 0; n2 < 4; ++n2) bfv[n2] = *reinterpret_cast<const short8*>(&Bl[wc + n2*16 + l16][kh*8]);
    #pragma unroll
    for (int m = 0; m < 4; ++m)
      #pragma unroll
      for (int n2 = 0; n2 < 4; ++n2)
        acc[m][n2] = __builtin_amdgcn_mfma_f32_16x16x32_bf16(af[m], bfv[n2], acc[m][n2], 0, 0, 0);
  }

  #pragma unroll
  for (int n2 = 0; n2 < 4; ++n2){
    int col = cbase + wc + n2*16 + l16;
    float bv = bias ? bias[col] : 0.f;
    #pragma unroll
    for (int m = 0; m < 4; ++m){
      #pragma unroll
      for (int i = 0; i < 4; ++i){
        int row = rbase + wr + m*16 + kh*4 + i;
        if (row >= M) continue;
        float v = acc[m][n2][i] + bv;
        if (rowscale) v *= rowscale[row];
        if (relu) v = fmaxf(v, 0.f);
        if (Cf) Cf[(size_t)row*Nc + col] = v;
        if (Cb) Cb[(size_t)row*Nc + col] = f2bf(v);
      }
    }
  }
}

// ---------------- tiled fp32 NT GEMM (small GEMMs) ----------------
__global__ __launch_bounds__(256) void k_gemm_nt(
    const float* __restrict__ A, const float* __restrict__ Bt,
    const float* __restrict__ bias, const float* __restrict__ Dadd,
    float* __restrict__ C, int M, int K, int Nc, int accum, int act)
{
  __shared__ float As[64][20];
  __shared__ float Bs[64][20];
  int tid = threadIdx.x;
  int rbase = blockIdx.y*64, cbase = blockIdx.x*64;
  int ty = tid>>4, tx = tid&15;
  int lr = tid>>2, lq = tid&3;
  float acc[4][4] = {};
  for (int k0 = 0; k0 < K; k0 += 16){
    float4 av = make_float4(0,0,0,0), bv = make_float4(0,0,0,0);
    int kk = k0 + lq*4;
    int ar = rbase + lr;
    if (ar < M && kk < K){
      if (kk + 3 < K) av = *reinterpret_cast<const float4*>(A + (size_t)ar*K + kk);
      else { float t0[4] = {0,0,0,0}; for (int i=0; i<4 && kk+i<K; ++i) t0[i] = A[(size_t)ar*K + kk + i];
             av = make_float4(t0[0],t0[1],t0[2],t0[3]); }
    }
    int br = cbase + lr;
    if (br < Nc && kk < K){
      if (kk + 3 < K) bv = *reinterpret_cast<const float4*>(Bt + (size_t)br*K + kk);
      else { float t0[4] = {0,0,0,0}; for (int i=0; i<4 && kk+i<K; ++i) t0[i] = Bt[(size_t)br*K + kk + i];
             bv = make_float4(t0[0],t0[1],t0[2],t0[3]); }
    }
    __syncthreads();
    *reinterpret_cast<float4*>(&As[lr][lq*4]) = av;
    *reinterpret_cast<float4*>(&Bs[lr][lq*4]) = bv;
    __syncthreads();
    #pragma unroll
    for (int kc = 0; kc < 16; kc += 4){
      float4 a4[4], b4[4];
      #pragma unroll
      for (int i=0;i<4;++i) a4[i] = *reinterpret_cast<float4*>(&As[ty*4+i][kc]);
      #pragma unroll
      for (int j=0;j<4;++j) b4[j] = *reinterpret_cast<float4*>(&Bs[tx*4+j][kc]);
      #pragma unroll
      for (int i=0;i<4;++i)
        #pragma unroll
        for (int j=0;j<4;++j)
          acc[i][j] += a4[i].x*b4[j].x + a4[i].y*b4[j].y + a4[i].z*b4[j].z + a4[i].w*b4[j].w;
    }
  }
  #pragma unroll
  for (int i=0;i<4;++i){
    int r = rbase + ty*4 + i;
    if (r >= M) continue;
    #pragma unroll
    for (int j=0;j<4;++j){
      int cc = cbase + tx*4 + j;
      if (cc >= Nc) continue;
      float v = acc[i][j];
      if (accum) v += C[(size_t)r*Nc + cc];
      if (bias)  v += bias[cc];
      if (Dadd)  v += Dadd[(size_t)r*Nc + cc];
      if (act == 1) v = (v > 0.f) ? v : 0.01f*v;
      C[(size_t)r*Nc + cc] = v;
    }
  }
}

// ---------------- pooling / LSTM / head ----------------
__global__ void k_sto(const unsigned short* __restrict__ wxb, const int* __restrict__ boffs,
                      float* __restrict__ sto){
  int b = blockIdx.x, c = threadIdx.x;
  int s = boffs[b], e2 = boffs[b+1];
  float acc = 0.f;
  for (int n=s; n<e2; ++n) acc += bf2f(wxb[(size_t)n*Hh + c]);
  sto[(size_t)b*Hh + c] = acc;
}

__global__ void k_bsum(const float* __restrict__ bih, const float* __restrict__ bhh,
                       float* __restrict__ bsum){
  int g = blockIdx.x*256 + threadIdx.x;
  if (g < 4*Hh) bsum[g] = bih[g] + bhh[g];
}

// gates -> c,h; writes h into qstar fp32 and qh bf16 (slots [0:256] and [512:768])
__global__ void k_lstm(const float* __restrict__ gates, float* __restrict__ cbuf,
                       float* __restrict__ hbuf, float* __restrict__ qstar,
                       unsigned short* __restrict__ qh){
  int idx = blockIdx.x*256 + threadIdx.x;
  if (idx >= Bb*Hh) return;
  int b = idx >> 8, ch = idx & 255;
  const float* g = gates + (size_t)b*4*Hh;
  float ig = sigf(g[ch]);
  float fg = sigf(g[Hh + ch]);
  float gg = tanhf(g[2*Hh + ch]);
  float og = sigf(g[3*Hh + ch]);
  float cn = fg*cbuf[idx] + ig*gg;
  float hn = og*tanhf(cn);
  cbuf[idx] = cn; hbuf[idx] = hn;
  qstar[(size_t)b*2*Hh + ch] = hn;
  unsigned short hb = f2bf(hn);
  qh[(size_t)b*3*Hh + ch] = hb;
  qh[(size_t)b*3*Hh + 2*Hh + ch] = hb;
}

__global__ void k_e(const unsigned short* __restrict__ wxb, const float* __restrict__ hbuf,
                    const int* __restrict__ batch, float* __restrict__ ebuf){
  int node = blockIdx.x*4 + (threadIdx.x >> 6);
  int lane = threadIdx.x & 63;
  if (node >= Nn) return;
  int b = batch[node];
  const unsigned short* w = wxb + (size_t)node*Hh;
  const float* h = hbuf + (size_t)b*Hh;
  float v = 0.f;
  #pragma unroll
  for (int i=0;i<4;++i) v += bf2f(w[lane + 64*i])*h[lane + 64*i];
  for (int off=32; off; off>>=1) v += __shfl_down(v, off, 64);
  if (lane == 0) ebuf[node] = v;
}

__global__ void k_attn(const float* __restrict__ ebuf, const unsigned short* __restrict__ wxb,
                       const int* __restrict__ boffs, float* __restrict__ pbuf,
                       float* __restrict__ qstar, unsigned short* __restrict__ qh){
  __shared__ float red[256];
  int b = blockIdx.x, tid = threadIdx.x;
  int s = boffs[b], e2 = boffs[b+1];
  float m = -INFINITY;
  for (int n=s+tid; n<e2; n+=256) m = fmaxf(m, ebuf[n]);
  red[tid] = m; __syncthreads();
  for (int st=128; st>0; st>>=1){ if (tid<st) red[tid] = fmaxf(red[tid], red[tid+st]); __syncthreads(); }
  m = red[0]; __syncthreads();
  float sum = 0.f;
  for (int n=s+tid; n<e2; n+=256){ float p = expf(ebuf[n]-m); pbuf[n] = p; sum += p; }
  red[tid] = sum; __syncthreads();
  for (int st=128; st>0; st>>=1){ if (tid<st) red[tid] += red[tid+st]; __syncthreads(); }
  float inv = 1.f/(red[0] + 1e-16f);
  float racc = 0.f;
  for (int n=s; n<e2; ++n) racc += pbuf[n]*bf2f(wxb[(size_t)n*Hh + tid]);
  float r = racc*inv;
  qstar[(size_t)b*2*Hh + Hh + tid] = r;
  qh[(size_t)b*3*Hh + Hh + tid] = f2bf(r);
}

__global__ void k_norm(float* __restrict__ mean){
  __shared__ float red[256];
  int b = blockIdx.x, tid = threadIdx.x;
  float v = mean[(size_t)b*Hh + tid];
  red[tid] = v*v; __syncthreads();
  for (int st=128; st>0; st>>=1){ if (tid<st) red[tid] += red[tid+st]; __syncthreads(); }
  float nrm = fmaxf(sqrtf(red[0]), 1e-12f);
  mean[(size_t)b*Hh + tid] = v/nrm;
}

__global__ void k_out(const float* __restrict__ y1, const float* __restrict__ p2W,
                      const float* __restrict__ p2b, float* __restrict__ out){
  __shared__ float red[128];
  int b = blockIdx.x, tid = threadIdx.x;
  float v = y1[(size_t)b*128 + tid]*p2W[tid];
  red[tid] = v; __syncthreads();
  for (int st=64; st>0; st>>=1){ if (tid<st) red[tid] += red[tid+st]; __syncthreads(); }
  if (tid == 0) out[b] = red[0] + p2b[0];
}

// ---------------- launch ----------------
extern "C" void kernel_launch(void* const* d_in, const int* in_sizes, int n_in,
                              void* d_out, int out_size, void* d_ws, size_t ws_size,
                              hipStream_t stream) {
  const float* weight   = (const float*)d_in[0];
  const int*   sto_x    = (const int*)  d_in[1];
  const int*   ei       = (const int*)  d_in[2];
  const float* sto_w    = (const float*)d_in[3];
  const int*   batch    = (const int*)  d_in[4];
  const float* gW0 = (const float*)d_in[5];   const float* gb0 = (const float*)d_in[6];
  const float* gW1 = (const float*)d_in[7];   const float* gb1 = (const float*)d_in[8];
  const float* gW2 = (const float*)d_in[9];   const float* gb2 = (const float*)d_in[10];
  const float* Wih = (const float*)d_in[11];  const float* Whh = (const float*)d_in[12];
  const float* bih = (const float*)d_in[13];  const float* bhh = (const float*)d_in[14];
  const float* mW  = (const float*)d_in[15];  const float* mb  = (const float*)d_in[16];
  const float* p0W = (const float*)d_in[17];  const float* p0b = (const float*)d_in[18];
  const float* p1W = (const float*)d_in[19];  const float* p1b = (const float*)d_in[20];
  const float* p2W = (const float*)d_in[21];  const float* p2b = (const float*)d_in[22];
  float* out = (float*)d_out;

  // workspace carve (256B aligned)
  char* w = (char*)d_ws;
  auto alloc = [&](size_t bytes)->char*{ char* p = w; w += (bytes + 255) & ~size_t(255); return p; };
  unsigned short* Xb = (unsigned short*)alloc((size_t)Nn*Hh*2);  // node activations (bf16)
  unsigned short* Tb = (unsigned short*)alloc((size_t)Nn*Hh*2);  // aggregate (bf16)
  float* WG0   = (float*)alloc((size_t)Vv*Hh*4);
  unsigned short* WG0b = (unsigned short*)alloc((size_t)Vv*Hh*2);
  float* gW0t  = (float*)alloc((size_t)Hh*DIN*4);
  unsigned short* gW1tb = (unsigned short*)alloc((size_t)Hh*Hh*2);
  unsigned short* gW2tb = (unsigned short*)alloc((size_t)Hh*Hh*2);
  unsigned short* Wpb   = (unsigned short*)alloc((size_t)4*Hh*3*Hh*2);  // [1024][768]
  int*   counts= (int*)  alloc((size_t)Nn*4);
  int*   offs  = (int*)  alloc((size_t)(Nn+1)*4);
  int*   fptr  = (int*)  alloc((size_t)Nn*4);
  float* dinv  = (float*)alloc((size_t)Nn*4);
  int*   srcs  = (int*)  alloc((size_t)Ee*4);
  float* norms = (float*)alloc((size_t)Ee*4);
  int*   boffs = (int*)  alloc((size_t)(Bb+1)*4);
  float* ebuf  = (float*)alloc((size_t)Nn*4);
  float* pbuf  = (float*)alloc((size_t)Nn*4);
  float* sto   = (float*)alloc((size_t)Bb*Hh*4);
  float* hbuf  = (float*)alloc((size_t)Bb*Hh*4);
  float* cbuf  = (float*)alloc((size_t)Bb*Hh*4);
  float* qstar = (float*)alloc((size_t)Bb*2*Hh*4);
  unsigned short* qh = (unsigned short*)alloc((size_t)Bb*3*Hh*2);   // [h | r | h] bf16
  float* gates = (float*)alloc((size_t)Bb*4*Hh*4);
  float* bsum  = (float*)alloc((size_t)4*Hh*4);
  float* meanb = (float*)alloc((size_t)Bb*Hh*4);
  float* y0    = (float*)alloc((size_t)Bb*128*4);
  float* y1    = (float*)alloc((size_t)Bb*128*4);

  auto gemm = [&](const float* A, const float* Bt, const float* bias, const float* Dadd,
                  float* C, int M, int K, int Nc, int accum, int act){
    dim3 g((Nc+63)/64, (M+63)/64);
    k_gemm_nt<<<g, 256, 0, stream>>>(A, Bt, bias, Dadd, C, M, K, Nc, accum, act);
  };
  auto gemmb = [&](const unsigned short* A, const unsigned short* Bt, const float* bias,
                   const float* rowscale, float* Cf, unsigned short* Cb,
                   int M, int K, int Nc, int relu){
    dim3 g(Nc/128, (M+127)/128);
    k_gemm_bf16<<<g, 256, 0, stream>>>(A, Bt, bias, rowscale, Cf, Cb, M, K, Nc, relu);
  };

  // per-launch state init (deterministic every call)
  hipMemsetAsync(counts, 0, (size_t)Nn*4, stream);
  hipMemsetAsync(cbuf,  0, (size_t)Bb*Hh*4, stream);
  hipMemsetAsync(qh,    0, (size_t)Bb*3*Hh*2, stream);

  // weight prep
  k_transpose<<<(DIN*Hh+255)/256, 256, 0, stream>>>(gW0, gW0t, DIN, Hh);
  k_transpose_b<<<(Hh*Hh+255)/256, 256, 0, stream>>>(gW1, gW1tb, Hh, Hh);
  k_transpose_b<<<(Hh*Hh+255)/256, 256, 0, stream>>>(gW2, gW2tb, Hh, Hh);
  k_packW<<<(4*Hh*3*Hh+255)/256, 256, 0, stream>>>(Wih, Whh, Wpb);

  // graph structure
  k_count<<<(Ee+255)/256, 256, 0, stream>>>(ei + Ee, counts);
  k_dinv<<<(Nn+255)/256, 256, 0, stream>>>(counts, dinv);
  k_scan<<<1, 1024, 0, stream>>>(counts, offs);
  k_copyi<<<(Nn+255)/256, 256, 0, stream>>>(offs, fptr, Nn);
  k_fill<<<(Ee+255)/256, 256, 0, stream>>>(ei, dinv, fptr, srcs, norms);
  k_boffs<<<(Bb+256)/256, 256, 0, stream>>>(batch, boffs);

  // WG0 = weight @ gW0 (103x256 table), cast to bf16; layer 0 gather
  gemm(weight, gW0t, nullptr, nullptr, WG0, Vv, DIN, Hh, 0, 0);
  k_castb<<<(Vv*Hh+255)/256, 256, 0, stream>>>(WG0, WG0b, Vv*Hh);
  k_conv0<<<Nn, Hh, 0, stream>>>(WG0b, sto_x, offs, srcs, norms, dinv, gb0, Xb);

  // layers 1,2: aggregate-first, GEMM with fused epilogue
  k_agg<<<Nn, Hh, 0, stream>>>(Xb, offs, srcs, norms, dinv, Tb);
  gemmb(Tb, gW1tb, gb1, nullptr, nullptr, Xb, Nn, Hh, Hh, 1);          // X = relu(agg@W1+b1)
  k_agg<<<Nn, Hh, 0, stream>>>(Xb, offs, srcs, norms, dinv, Tb);
  gemmb(Tb, gW2tb, gb2, sto_w, nullptr, Xb, Nn, Hh, Hh, 0);            // X = wx (bf16)

  // graph sums
  k_sto<<<Bb, Hh, 0, stream>>>(Xb, boffs, sto);
  k_bsum<<<(4*Hh+255)/256, 256, 0, stream>>>(bih, bhh, bsum);

  // Set2Set (2 steps), fused gate GEMM: [h|r|h] @ [Wih|Whh]^T
  for (int t = 0; t < 2; ++t){
    gemmb(qh, Wpb, bsum, nullptr, gates, nullptr, Bb, 3*Hh, 4*Hh, 0);
    k_lstm<<<(Bb*Hh+255)/256, 256, 0, stream>>>(gates, cbuf, hbuf, qstar, qh);
    k_e<<<(Nn+3)/4, 256, 0, stream>>>(Xb, hbuf, batch, ebuf);
    k_attn<<<Bb, Hh, 0, stream>>>(ebuf, Xb, boffs, pbuf, qstar, qh);
  }

  // head (fp32)
  gemm(qstar, mW, mb, sto, meanb, Bb, 2*Hh, Hh, 0, 0);
  k_norm<<<Bb, Hh, 0, stream>>>(meanb);
  gemm(meanb, p0W, p0b, nullptr, y0, Bb, Hh, 128, 0, 1);
  gemm(y0, p1W, p1b, nullptr, y1, Bb, 128, 128, 0, 1);
  k_out<<<Bb, 128, 0, stream>>>(y1, p2W, p2b, out);
}

// Round 4
// 895.487 us; speedup vs baseline: 2.2732x; 1.3785x over previous
//
#include <hip/hip_runtime.h>
#include <math.h>

// Problem constants
constexpr int Nn  = 100000;  // nodes
constexpr int Ee  = 800000;  // edges
constexpr int Bb  = 4096;    // graphs
constexpr int Vv  = 103;     // vocab
constexpr int DIN = 200;     // embedding dim
constexpr int Hh  = 256;     // hidden
constexpr int KV  = 128;     // padded vocab dim for hist GEMM

using short8 = __attribute__((ext_vector_type(8))) short;
using f32x4  = __attribute__((ext_vector_type(4))) float;

__device__ __forceinline__ float sigf(float x){ return 1.f/(1.f+expf(-x)); }

__device__ __forceinline__ unsigned short f2bf(float f){
  unsigned int u = __float_as_uint(f);
  u += 0x7FFFu + ((u >> 16) & 1u);
  return (unsigned short)(u >> 16);
}
__device__ __forceinline__ float bf2f(unsigned int u){
  return __uint_as_float((u & 0xFFFFu) << 16);
}

// ---------------- small utility kernels ----------------
__global__ void k_transpose(const float* __restrict__ in, float* __restrict__ out, int R, int C){
  int idx = blockIdx.x*256 + threadIdx.x;
  if (idx >= R*C) return;
  int r = idx / C, c = idx % C;
  out[(size_t)c*R + r] = in[(size_t)r*C + c];
}

__global__ void k_transpose_b(const float* __restrict__ in, unsigned short* __restrict__ out, int R, int C){
  int idx = blockIdx.x*256 + threadIdx.x;
  if (idx >= R*C) return;
  int r = idx / C, c = idx % C;
  out[(size_t)c*R + r] = f2bf(in[(size_t)r*C + c]);
}

__global__ void k_castb(const float* __restrict__ in, unsigned short* __restrict__ out, int n){
  int i = blockIdx.x*256 + threadIdx.x;
  if (i < n) out[i] = f2bf(in[i]);
}

// WG0 fp32 [103][256] -> bf16 [256][128] (padded, transposed: out[n][k] = WG0[k][n])
__global__ void k_wg0t(const float* __restrict__ WG0, unsigned short* __restrict__ WG0tb){
  int i = blockIdx.x*256 + threadIdx.x;
  if (i >= Hh*KV) return;
  int n = i >> 7, k = i & (KV-1);
  float v = (k < Vv) ? WG0[(size_t)k*Hh + n] : 0.f;
  WG0tb[i] = f2bf(v);
}

// pack [Wih | Whh] -> bf16 [1024][768]
__global__ void k_packW(const float* __restrict__ Wih, const float* __restrict__ Whh,
                        unsigned short* __restrict__ Wp){
  int i = blockIdx.x*256 + threadIdx.x;
  if (i >= 4*Hh*3*Hh) return;
  int g = i / (3*Hh), j = i % (3*Hh);
  float v = (j < 2*Hh) ? Wih[(size_t)g*2*Hh + j] : Whh[(size_t)g*Hh + (j - 2*Hh)];
  Wp[i] = f2bf(v);
}

__global__ void k_count(const int* __restrict__ dst, int* __restrict__ counts){
  int e = blockIdx.x*256 + threadIdx.x;
  if (e < Ee) atomicAdd(&counts[dst[e]], 1);
}

__global__ void k_dinv(const int* __restrict__ counts, float* __restrict__ dinv){
  int n = blockIdx.x*256 + threadIdx.x;
  if (n < Nn) dinv[n] = rsqrtf((float)(counts[n] + 1));
}

// single-block exclusive scan of counts[0..Nn) -> offs[0..Nn]
__global__ void k_scan(const int* __restrict__ counts, int* __restrict__ offs){
  __shared__ int part[1024];
  int tid = threadIdx.x;
  const int chunk = (Nn + 1023)/1024;
  int s = tid*chunk, e2 = min(s+chunk, Nn);
  int sum = 0;
  for (int i=s; i<e2; ++i) sum += counts[i];
  part[tid] = sum; __syncthreads();
  for (int off=1; off<1024; off<<=1){
    int t = (tid>=off) ? part[tid-off] : 0;
    __syncthreads();
    part[tid] += t;
    __syncthreads();
  }
  int run = part[tid] - sum;
  for (int i=s; i<e2; ++i){ offs[i] = run; run += counts[i]; }
  if (tid == 1023) offs[Nn] = part[1023];
}

__global__ void k_copyi(const int* __restrict__ a, int* __restrict__ b, int n){
  int i = blockIdx.x*256 + threadIdx.x;
  if (i < n) b[i] = a[i];
}

__global__ void k_fill(const int* __restrict__ ei, const float* __restrict__ dinv,
                       int* __restrict__ fptr, int* __restrict__ srcs, float* __restrict__ norms){
  int e = blockIdx.x*256 + threadIdx.x;
  if (e >= Ee) return;
  int s = ei[e], d = ei[Ee + e];
  int pos = atomicAdd(&fptr[d], 1);
  srcs[pos]  = s;
  norms[pos] = dinv[s]*dinv[d];
}

__global__ void k_boffs(const int* __restrict__ batch, int* __restrict__ boffs){
  int b = blockIdx.x*256 + threadIdx.x;
  if (b > Bb) return;
  int lo = 0, hi = Nn;
  while (lo < hi){ int mid = (lo+hi)>>1; if (batch[mid] < b) lo = mid+1; else hi = mid; }
  boffs[b] = lo;
}

// ---------------- layer 0: vocab histogram (wave per node) ----------------
// V[n][v] = dinv[n]^2 * 1[vocab(n)=v] + sum_csr norm_k * 1[vocab(src_k)=v], bf16 out
__global__ void k_hist(const int* __restrict__ sto_x, const int* __restrict__ offs,
                       const int* __restrict__ srcs, const float* __restrict__ norms,
                       const float* __restrict__ dinv, unsigned short* __restrict__ Vb){
  __shared__ float hist[4][KV];
  int wid = threadIdx.x >> 6, lane = threadIdx.x & 63;
  int n = blockIdx.x*4 + wid;
  hist[wid][lane] = 0.f; hist[wid][lane+64] = 0.f;
  __syncthreads();
  int s = offs[n], e = offs[n+1];
  for (int k = s + lane; k < e; k += 64){
    int r2 = sto_x[srcs[k]]; r2 = (r2 == 0) ? (Vv-1) : r2-1;
    atomicAdd(&hist[wid][r2], norms[k]);
  }
  if (lane == 0){
    int r0 = sto_x[n]; r0 = (r0 == 0) ? (Vv-1) : r0-1;
    float dn = dinv[n];
    atomicAdd(&hist[wid][r0], dn*dn);
  }
  __syncthreads();
  unsigned int p = ((unsigned int)f2bf(hist[wid][2*lane+1]) << 16) | f2bf(hist[wid][2*lane]);
  ((unsigned int*)Vb)[(size_t)n*(KV/2) + lane] = p;
}

// ---------------- GCN aggregate (wave per node, uint2 lanes) ----------------
__global__ void k_agg(const unsigned short* __restrict__ Xb, const int* __restrict__ offs,
                      const int* __restrict__ srcs, const float* __restrict__ norms,
                      const float* __restrict__ dinv, unsigned short* __restrict__ T){
  int wid = threadIdx.x >> 6, lane = threadIdx.x & 63;
  int n = blockIdx.x*4 + wid;
  const uint2* Xv = (const uint2*)Xb;
  uint2 v = Xv[(size_t)n*64 + lane];
  float dn = dinv[n]; float s2 = dn*dn;
  float a0 = bf2f(v.x)*s2, a1 = bf2f(v.x>>16)*s2;
  float a2 = bf2f(v.y)*s2, a3 = bf2f(v.y>>16)*s2;
  int s = offs[n], e = offs[n+1];
  int k = s;
  for (; k + 1 < e; k += 2){
    int s0 = srcs[k], s1 = srcs[k+1];
    float n0 = norms[k], n1 = norms[k+1];
    uint2 g0 = Xv[(size_t)s0*64 + lane];
    uint2 g1 = Xv[(size_t)s1*64 + lane];
    a0 += bf2f(g0.x)*n0; a1 += bf2f(g0.x>>16)*n0;
    a2 += bf2f(g0.y)*n0; a3 += bf2f(g0.y>>16)*n0;
    a0 += bf2f(g1.x)*n1; a1 += bf2f(g1.x>>16)*n1;
    a2 += bf2f(g1.y)*n1; a3 += bf2f(g1.y>>16)*n1;
  }
  if (k < e){
    uint2 g0 = Xv[(size_t)srcs[k]*64 + lane];
    float n0 = norms[k];
    a0 += bf2f(g0.x)*n0; a1 += bf2f(g0.x>>16)*n0;
    a2 += bf2f(g0.y)*n0; a3 += bf2f(g0.y>>16)*n0;
  }
  uint2 o;
  o.x = (unsigned int)f2bf(a0) | ((unsigned int)f2bf(a1) << 16);
  o.y = (unsigned int)f2bf(a2) | ((unsigned int)f2bf(a3) << 16);
  ((uint2*)T)[(size_t)n*64 + lane] = o;
}

// ---------------- bf16 MFMA NT GEMM, 128x128 tile ----------------
// out[m][n] = epi( sum_k A[m*lda+k]*Bt[n*K+k] + bias[n] + addf[m*Nc+n] ), epi: *rowscale[m], relu
__global__ __launch_bounds__(256) void k_gemm_bf16(
    const unsigned short* __restrict__ A, int lda,
    const unsigned short* __restrict__ Bt,
    const float* __restrict__ bias, const float* __restrict__ rowscale,
    const float* __restrict__ addf,
    float* __restrict__ Cf, unsigned short* __restrict__ Cb,
    int M, int K, int Nc, int relu)
{
  __shared__ unsigned short Al[128][40];
  __shared__ unsigned short Bl[128][40];
  int tid = threadIdx.x;
  int w = tid >> 6, lane = tid & 63;
  int wr = (w >> 1)*64, wc = (w & 1)*64;
  int l16 = lane & 15, kh = lane >> 4;
  int rbase = blockIdx.y*128, cbase = blockIdx.x*128;
  int sr = tid >> 2, sb = tid & 3;

  f32x4 acc[4][4] = {};

  for (int k0 = 0; k0 < K; k0 += 32){
    int kk = k0 + sb*8;
    uint4 a0 = make_uint4(0,0,0,0), a1 = make_uint4(0,0,0,0);
    int ar0 = rbase + sr, ar1 = rbase + sr + 64;
    if (ar0 < M) a0 = *reinterpret_cast<const uint4*>(A + (size_t)ar0*lda + kk);
    if (ar1 < M) a1 = *reinterpret_cast<const uint4*>(A + (size_t)ar1*lda + kk);
    uint4 b0 = *reinterpret_cast<const uint4*>(Bt + (size_t)(cbase + sr)*K + kk);
    uint4 b1 = *reinterpret_cast<const uint4*>(Bt + (size_t)(cbase + sr + 64)*K + kk);
    __syncthreads();
    *reinterpret_cast<uint4*>(&Al[sr][sb*8])    = a0;
    *reinterpret_cast<uint4*>(&Al[sr+64][sb*8]) = a1;
    *reinterpret_cast<uint4*>(&Bl[sr][sb*8])    = b0;
    *reinterpret_cast<uint4*>(&Bl[sr+64][sb*8]) = b1;
    __syncthreads();

    short8 af[4], bfv[4];
    #pragma unroll
    for (int m = 0; m < 4; ++m) af[m] = *reinterpret_cast<const short8*>(&Al[wr + m*16 + l16][kh*8]);
    #pragma unroll
    for (int n2 = 0; n2 < 4; ++n2) bfv[n2] = *reinterpret_cast<const short8*>(&Bl[wc + n2*16 + l16][kh*8]);
    #pragma unroll
    for (int m = 0; m < 4; ++m)
      #pragma unroll
      for (int n2 = 0; n2 < 4; ++n2)
        acc[m][n2] = __builtin_amdgcn_mfma_f32_16x16x32_bf16(af[m], bfv[n2], acc[m][n2], 0, 0, 0);
  }

  #pragma unroll
  for (int n2 = 0; n2 < 4; ++n2){
    int col = cbase + wc + n2*16 + l16;
    float bv = bias ? bias[col] : 0.f;
    #pragma unroll
    for (int m = 0; m < 4; ++m){
      #pragma unroll
      for (int i = 0; i < 4; ++i){
        int row = rbase + wr + m*16 + kh*4 + i;
        if (row >= M) continue;
        float v = acc[m][n2][i] + bv;
        if (addf) v += addf[(size_t)row*Nc + col];
        if (rowscale) v *= rowscale[row];
        if (relu) v = fmaxf(v, 0.f);
        if (Cf) Cf[(size_t)row*Nc + col] = v;
        if (Cb) Cb[(size_t)row*Nc + col] = f2bf(v);
      }
    }
  }
}

// ---------------- tiled fp32 NT GEMM (small GEMMs) ----------------
__global__ __launch_bounds__(256) void k_gemm_nt(
    const float* __restrict__ A, const float* __restrict__ Bt,
    const float* __restrict__ bias, const float* __restrict__ Dadd,
    float* __restrict__ C, int M, int K, int Nc, int accum, int act)
{
  __shared__ float As[64][20];
  __shared__ float Bs[64][20];
  int tid = threadIdx.x;
  int rbase = blockIdx.y*64, cbase = blockIdx.x*64;
  int ty = tid>>4, tx = tid&15;
  int lr = tid>>2, lq = tid&3;
  float acc[4][4] = {};
  for (int k0 = 0; k0 < K; k0 += 16){
    float4 av = make_float4(0,0,0,0), bv = make_float4(0,0,0,0);
    int kk = k0 + lq*4;
    int ar = rbase + lr;
    if (ar < M && kk < K){
      if (kk + 3 < K) av = *reinterpret_cast<const float4*>(A + (size_t)ar*K + kk);
      else { float t0[4] = {0,0,0,0}; for (int i=0; i<4 && kk+i<K; ++i) t0[i] = A[(size_t)ar*K + kk + i];
             av = make_float4(t0[0],t0[1],t0[2],t0[3]); }
    }
    int br = cbase + lr;
    if (br < Nc && kk < K){
      if (kk + 3 < K) bv = *reinterpret_cast<const float4*>(Bt + (size_t)br*K + kk);
      else { float t0[4] = {0,0,0,0}; for (int i=0; i<4 && kk+i<K; ++i) t0[i] = Bt[(size_t)br*K + kk + i];
             bv = make_float4(t0[0],t0[1],t0[2],t0[3]); }
    }
    __syncthreads();
    *reinterpret_cast<float4*>(&As[lr][lq*4]) = av;
    *reinterpret_cast<float4*>(&Bs[lr][lq*4]) = bv;
    __syncthreads();
    #pragma unroll
    for (int kc = 0; kc < 16; kc += 4){
      float4 a4[4], b4[4];
      #pragma unroll
      for (int i=0;i<4;++i) a4[i] = *reinterpret_cast<float4*>(&As[ty*4+i][kc]);
      #pragma unroll
      for (int j=0;j<4;++j) b4[j] = *reinterpret_cast<float4*>(&Bs[tx*4+j][kc]);
      #pragma unroll
      for (int i=0;i<4;++i)
        #pragma unroll
        for (int j=0;j<4;++j)
          acc[i][j] += a4[i].x*b4[j].x + a4[i].y*b4[j].y + a4[i].z*b4[j].z + a4[i].w*b4[j].w;
    }
  }
  #pragma unroll
  for (int i=0;i<4;++i){
    int r = rbase + ty*4 + i;
    if (r >= M) continue;
    #pragma unroll
    for (int j=0;j<4;++j){
      int cc = cbase + tx*4 + j;
      if (cc >= Nc) continue;
      float v = acc[i][j];
      if (accum) v += C[(size_t)r*Nc + cc];
      if (bias)  v += bias[cc];
      if (Dadd)  v += Dadd[(size_t)r*Nc + cc];
      if (act == 1) v = (v > 0.f) ? v : 0.01f*v;
      C[(size_t)r*Nc + cc] = v;
    }
  }
}

// ---------------- pooling / LSTM / head ----------------
// wave per graph, lane holds 4 contiguous channels
__global__ void k_sto(const unsigned short* __restrict__ wxb, const int* __restrict__ boffs,
                      float* __restrict__ sto){
  int wid = threadIdx.x >> 6, lane = threadIdx.x & 63;
  int g = blockIdx.x*4 + wid;
  if (g >= Bb) return;
  const uint2* Xv = (const uint2*)wxb;
  int s = boffs[g], e = boffs[g+1];
  float a0=0.f, a1=0.f, a2=0.f, a3=0.f;
  for (int n=s; n<e; ++n){
    uint2 v = Xv[(size_t)n*64 + lane];
    a0 += bf2f(v.x); a1 += bf2f(v.x>>16);
    a2 += bf2f(v.y); a3 += bf2f(v.y>>16);
  }
  ((float4*)sto)[(size_t)g*64 + lane] = make_float4(a0,a1,a2,a3);
}

__global__ void k_bsum(const float* __restrict__ bih, const float* __restrict__ bhh,
                       float* __restrict__ bsum){
  int g = blockIdx.x*256 + threadIdx.x;
  if (g < 4*Hh) bsum[g] = bih[g] + bhh[g];
}

// gates -> c,h; writes h into qh bf16 (slots [0:256] and [512:768]) and hbuf fp32
__global__ void k_lstm(const float* __restrict__ gates, float* __restrict__ cbuf,
                       float* __restrict__ hbuf, unsigned short* __restrict__ qh){
  int idx = blockIdx.x*256 + threadIdx.x;
  if (idx >= Bb*Hh) return;
  int b = idx >> 8, ch = idx & 255;
  const float* g = gates + (size_t)b*4*Hh;
  float ig = sigf(g[ch]);
  float fg = sigf(g[Hh + ch]);
  float gg = tanhf(g[2*Hh + ch]);
  float og = sigf(g[3*Hh + ch]);
  float cn = fg*cbuf[idx] + ig*gg;
  float hn = og*tanhf(cn);
  cbuf[idx] = cn; hbuf[idx] = hn;
  unsigned short hb = f2bf(hn);
  qh[(size_t)b*3*Hh + ch] = hb;
  qh[(size_t)b*3*Hh + 2*Hh + ch] = hb;
}

// wave per node: e[n] = dot(wx[n], h[batch[n]])
__global__ void k_e(const unsigned short* __restrict__ wxb, const float* __restrict__ hbuf,
                    const int* __restrict__ batch, float* __restrict__ ebuf){
  int node = blockIdx.x*4 + (threadIdx.x >> 6);
  int lane = threadIdx.x & 63;
  int b = batch[node];
  uint2 wv = ((const uint2*)wxb)[(size_t)node*64 + lane];
  float4 hv = ((const float4*)hbuf)[(size_t)b*64 + lane];
  float v = bf2f(wv.x)*hv.x + bf2f(wv.x>>16)*hv.y + bf2f(wv.y)*hv.z + bf2f(wv.y>>16)*hv.w;
  for (int off=32; off; off>>=1) v += __shfl_down(v, off, 64);
  if (lane == 0) ebuf[node] = v;
}

// wave per graph: softmax over nodes + weighted row sum, single pass
__global__ void k_attn(const float* __restrict__ ebuf, const unsigned short* __restrict__ wxb,
                       const int* __restrict__ boffs, unsigned short* __restrict__ qh){
  int wid = threadIdx.x >> 6, lane = threadIdx.x & 63;
  int g = blockIdx.x*4 + wid;
  if (g >= Bb) return;
  const uint2* Xv = (const uint2*)wxb;
  int s = boffs[g], e = boffs[g+1];
  float m = -INFINITY;
  for (int n=s+lane; n<e; n+=64) m = fmaxf(m, ebuf[n]);
  #pragma unroll
  for (int mask=32; mask; mask>>=1) m = fmaxf(m, __shfl_xor(m, mask, 64));
  float a0=0.f, a1=0.f, a2=0.f, a3=0.f, sum=0.f;
  for (int n=s; n<e; ++n){
    float p = expf(ebuf[n]-m);
    sum += p;
    uint2 v = Xv[(size_t)n*64 + lane];
    a0 += p*bf2f(v.x); a1 += p*bf2f(v.x>>16);
    a2 += p*bf2f(v.y); a3 += p*bf2f(v.y>>16);
  }
  float inv = 1.f/(sum + 1e-16f);
  a0 *= inv; a1 *= inv; a2 *= inv; a3 *= inv;
  uint2 o;
  o.x = (unsigned int)f2bf(a0) | ((unsigned int)f2bf(a1) << 16);
  o.y = (unsigned int)f2bf(a2) | ((unsigned int)f2bf(a3) << 16);
  // r slot: qh row [h | r | h], offset Hh, channels 4*lane..4*lane+3
  ((uint2*)(qh + (size_t)g*3*Hh + Hh))[lane] = o;
}

__global__ void k_norm(float* __restrict__ mean){
  __shared__ float red[256];
  int b = blockIdx.x, tid = threadIdx.x;
  float v = mean[(size_t)b*Hh + tid];
  red[tid] = v*v; __syncthreads();
  for (int st=128; st>0; st>>=1){ if (tid<st) red[tid] += red[tid+st]; __syncthreads(); }
  float nrm = fmaxf(sqrtf(red[0]), 1e-12f);
  mean[(size_t)b*Hh + tid] = v/nrm;
}

__global__ void k_out(const float* __restrict__ y1, const float* __restrict__ p2W,
                      const float* __restrict__ p2b, float* __restrict__ out){
  __shared__ float red[128];
  int b = blockIdx.x, tid = threadIdx.x;
  float v = y1[(size_t)b*128 + tid]*p2W[tid];
  red[tid] = v; __syncthreads();
  for (int st=64; st>0; st>>=1){ if (tid<st) red[tid] += red[tid+st]; __syncthreads(); }
  if (tid == 0) out[b] = red[0] + p2b[0];
}

// ---------------- launch ----------------
extern "C" void kernel_launch(void* const* d_in, const int* in_sizes, int n_in,
                              void* d_out, int out_size, void* d_ws, size_t ws_size,
                              hipStream_t stream) {
  const float* weight   = (const float*)d_in[0];
  const int*   sto_x    = (const int*)  d_in[1];
  const int*   ei       = (const int*)  d_in[2];
  const float* sto_w    = (const float*)d_in[3];
  const int*   batch    = (const int*)  d_in[4];
  const float* gW0 = (const float*)d_in[5];   const float* gb0 = (const float*)d_in[6];
  const float* gW1 = (const float*)d_in[7];   const float* gb1 = (const float*)d_in[8];
  const float* gW2 = (const float*)d_in[9];   const float* gb2 = (const float*)d_in[10];
  const float* Wih = (const float*)d_in[11];  const float* Whh = (const float*)d_in[12];
  const float* bih = (const float*)d_in[13];  const float* bhh = (const float*)d_in[14];
  const float* mW  = (const float*)d_in[15];  const float* mb  = (const float*)d_in[16];
  const float* p0W = (const float*)d_in[17];  const float* p0b = (const float*)d_in[18];
  const float* p1W = (const float*)d_in[19];  const float* p1b = (const float*)d_in[20];
  const float* p2W = (const float*)d_in[21];  const float* p2b = (const float*)d_in[22];
  float* out = (float*)d_out;

  // workspace carve (256B aligned)
  char* w = (char*)d_ws;
  auto alloc = [&](size_t bytes)->char*{ char* p = w; w += (bytes + 255) & ~size_t(255); return p; };
  unsigned short* Xb = (unsigned short*)alloc((size_t)Nn*Hh*2);   // node activations (bf16)
  unsigned short* Tb = (unsigned short*)alloc((size_t)Nn*Hh*2);   // aggregate (bf16)
  unsigned short* Vb = (unsigned short*)alloc((size_t)Nn*KV*2);   // vocab histogram (bf16)
  float* WG0   = (float*)alloc((size_t)Vv*Hh*4);
  unsigned short* WG0tb = (unsigned short*)alloc((size_t)Hh*KV*2);
  float* gW0t  = (float*)alloc((size_t)Hh*DIN*4);
  unsigned short* gW1tb = (unsigned short*)alloc((size_t)Hh*Hh*2);
  unsigned short* gW2tb = (unsigned short*)alloc((size_t)Hh*Hh*2);
  unsigned short* Wpb   = (unsigned short*)alloc((size_t)4*Hh*3*Hh*2);  // [1024][768]
  unsigned short* mWb   = (unsigned short*)alloc((size_t)Hh*2*Hh*2);    // [256][512]
  int*   counts= (int*)  alloc((size_t)Nn*4);
  int*   offs  = (int*)  alloc((size_t)(Nn+1)*4);
  int*   fptr  = (int*)  alloc((size_t)Nn*4);
  float* dinv  = (float*)alloc((size_t)Nn*4);
  int*   srcs  = (int*)  alloc((size_t)Ee*4);
  float* norms = (float*)alloc((size_t)Ee*4);
  int*   boffs = (int*)  alloc((size_t)(Bb+1)*4);
  float* ebuf  = (float*)alloc((size_t)Nn*4);
  float* sto   = (float*)alloc((size_t)Bb*Hh*4);
  float* hbuf  = (float*)alloc((size_t)Bb*Hh*4);
  float* cbuf  = (float*)alloc((size_t)Bb*Hh*4);
  unsigned short* qh = (unsigned short*)alloc((size_t)Bb*3*Hh*2);  // [h | r | h] bf16
  float* gates = (float*)alloc((size_t)Bb*4*Hh*4);
  float* bsum  = (float*)alloc((size_t)4*Hh*4);
  float* meanb = (float*)alloc((size_t)Bb*Hh*4);
  float* y0    = (float*)alloc((size_t)Bb*128*4);
  float* y1    = (float*)alloc((size_t)Bb*128*4);

  auto gemm = [&](const float* A, const float* Bt, const float* bias, const float* Dadd,
                  float* C, int M, int K, int Nc, int accum, int act){
    dim3 g((Nc+63)/64, (M+63)/64);
    k_gemm_nt<<<g, 256, 0, stream>>>(A, Bt, bias, Dadd, C, M, K, Nc, accum, act);
  };
  auto gemmb = [&](const unsigned short* A, int lda, const unsigned short* Bt,
                   const float* bias, const float* rowscale, const float* addf,
                   float* Cf, unsigned short* Cb, int M, int K, int Nc, int relu){
    dim3 g(Nc/128, (M+127)/128);
    k_gemm_bf16<<<g, 256, 0, stream>>>(A, lda, Bt, bias, rowscale, addf, Cf, Cb, M, K, Nc, relu);
  };

  // per-launch state init (deterministic every call)
  hipMemsetAsync(counts, 0, (size_t)Nn*4, stream);
  hipMemsetAsync(cbuf,  0, (size_t)Bb*Hh*4, stream);
  hipMemsetAsync(qh,    0, (size_t)Bb*3*Hh*2, stream);

  // weight prep
  k_transpose<<<(DIN*Hh+255)/256, 256, 0, stream>>>(gW0, gW0t, DIN, Hh);
  k_transpose_b<<<(Hh*Hh+255)/256, 256, 0, stream>>>(gW1, gW1tb, Hh, Hh);
  k_transpose_b<<<(Hh*Hh+255)/256, 256, 0, stream>>>(gW2, gW2tb, Hh, Hh);
  k_packW<<<(4*Hh*3*Hh+255)/256, 256, 0, stream>>>(Wih, Whh, Wpb);
  k_castb<<<(Hh*2*Hh+255)/256, 256, 0, stream>>>(mW, mWb, Hh*2*Hh);

  // graph structure
  k_count<<<(Ee+255)/256, 256, 0, stream>>>(ei + Ee, counts);
  k_dinv<<<(Nn+255)/256, 256, 0, stream>>>(counts, dinv);
  k_scan<<<1, 1024, 0, stream>>>(counts, offs);
  k_copyi<<<(Nn+255)/256, 256, 0, stream>>>(offs, fptr, Nn);
  k_fill<<<(Ee+255)/256, 256, 0, stream>>>(ei, dinv, fptr, srcs, norms);
  k_boffs<<<(Bb+256)/256, 256, 0, stream>>>(batch, boffs);

  // layer 0: WG0 = weight@gW0 (103x256), transpose to bf16 [256][128];
  // vocab histogram per node, then MFMA GEMM with bias+relu epilogue
  gemm(weight, gW0t, nullptr, nullptr, WG0, Vv, DIN, Hh, 0, 0);
  k_wg0t<<<(Hh*KV+255)/256, 256, 0, stream>>>(WG0, WG0tb);
  k_hist<<<Nn/4, 256, 0, stream>>>(sto_x, offs, srcs, norms, dinv, Vb);
  gemmb(Vb, KV, WG0tb, gb0, nullptr, nullptr, nullptr, Xb, Nn, KV, Hh, 1);

  // layers 1,2: aggregate-first, GEMM with fused epilogue
  k_agg<<<Nn/4, 256, 0, stream>>>(Xb, offs, srcs, norms, dinv, Tb);
  gemmb(Tb, Hh, gW1tb, gb1, nullptr, nullptr, nullptr, Xb, Nn, Hh, Hh, 1);
  k_agg<<<Nn/4, 256, 0, stream>>>(Xb, offs, srcs, norms, dinv, Tb);
  gemmb(Tb, Hh, gW2tb, gb2, sto_w, nullptr, nullptr, Xb, Nn, Hh, Hh, 0);  // Xb = wx

  // graph sums
  k_sto<<<Bb/4, 256, 0, stream>>>(Xb, boffs, sto);
  k_bsum<<<(4*Hh+255)/256, 256, 0, stream>>>(bih, bhh, bsum);

  // Set2Set (2 steps), fused gate GEMM: [h|r] @ [Wih|Whh]^T (A rows stride 768)
  for (int t = 0; t < 2; ++t){
    gemmb(qh, 3*Hh, Wpb, bsum, nullptr, nullptr, gates, nullptr, Bb, 3*Hh, 4*Hh, 0);
    k_lstm<<<(Bb*Hh+255)/256, 256, 0, stream>>>(gates, cbuf, hbuf, qh);
    k_e<<<Nn/4, 256, 0, stream>>>(Xb, hbuf, batch, ebuf);
    k_attn<<<Bb/4, 256, 0, stream>>>(ebuf, Xb, boffs, qh);
  }

  // head: mean = [h|r]@mW^T + mb + sto (bf16 MFMA), then normalize + fp32 MLP
  gemmb(qh, 3*Hh, mWb, mb, nullptr, sto, meanb, nullptr, Bb, 2*Hh, Hh, 0);
  k_norm<<<Bb, Hh, 0, stream>>>(meanb);
  gemm(meanb, p0W, p0b, nullptr, y0, Bb, Hh, 128, 0, 1);
  gemm(y0, p1W, p1b, nullptr, y1, Bb, 128, 128, 0, 1);
  k_out<<<Bb, 128, 0, stream>>>(y1, p2W, p2b, out);
}

// Round 5
// 740.034 us; speedup vs baseline: 2.7508x; 1.2101x over previous
//
#include <hip/hip_runtime.h>
#include <math.h>

// Problem constants
constexpr int Nn  = 100000;  // nodes
constexpr int Ee  = 800000;  // edges
constexpr int Bb  = 4096;    // graphs
constexpr int Vv  = 103;     // vocab
constexpr int DIN = 200;     // embedding dim
constexpr int Hh  = 256;     // hidden
constexpr int KV  = 128;     // padded vocab dim for hist GEMM

constexpr int SCHUNK = 1024;                       // elements per scan block
constexpr int NSCAN  = (Nn + SCHUNK - 1)/SCHUNK;   // 98 blocks

using short8 = __attribute__((ext_vector_type(8))) short;
using f32x4  = __attribute__((ext_vector_type(4))) float;

__device__ __forceinline__ float sigf(float x){ return 1.f/(1.f+expf(-x)); }

__device__ __forceinline__ unsigned short f2bf(float f){
  unsigned int u = __float_as_uint(f);
  u += 0x7FFFu + ((u >> 16) & 1u);
  return (unsigned short)(u >> 16);
}
__device__ __forceinline__ float bf2f(unsigned int u){
  return __uint_as_float((u & 0xFFFFu) << 16);
}

// ---------------- small utility kernels ----------------
__global__ void k_transpose(const float* __restrict__ in, float* __restrict__ out, int R, int C){
  int idx = blockIdx.x*256 + threadIdx.x;
  if (idx >= R*C) return;
  int r = idx / C, c = idx % C;
  out[(size_t)c*R + r] = in[(size_t)r*C + c];
}

__global__ void k_transpose_b(const float* __restrict__ in, unsigned short* __restrict__ out, int R, int C){
  int idx = blockIdx.x*256 + threadIdx.x;
  if (idx >= R*C) return;
  int r = idx / C, c = idx % C;
  out[(size_t)c*R + r] = f2bf(in[(size_t)r*C + c]);
}

__global__ void k_castb(const float* __restrict__ in, unsigned short* __restrict__ out, int n){
  int i = blockIdx.x*256 + threadIdx.x;
  if (i < n) out[i] = f2bf(in[i]);
}

// WG0 fp32 [103][256] -> bf16 [256][128] (padded, transposed: out[n][k] = WG0[k][n])
__global__ void k_wg0t(const float* __restrict__ WG0, unsigned short* __restrict__ WG0tb){
  int i = blockIdx.x*256 + threadIdx.x;
  if (i >= Hh*KV) return;
  int n = i >> 7, k = i & (KV-1);
  float v = (k < Vv) ? WG0[(size_t)k*Hh + n] : 0.f;
  WG0tb[i] = f2bf(v);
}

// pack [Wih | Whh] -> bf16 [1024][768]
__global__ void k_packW(const float* __restrict__ Wih, const float* __restrict__ Whh,
                        unsigned short* __restrict__ Wp){
  int i = blockIdx.x*256 + threadIdx.x;
  if (i >= 4*Hh*3*Hh) return;
  int g = i / (3*Hh), j = i % (3*Hh);
  float v = (j < 2*Hh) ? Wih[(size_t)g*2*Hh + j] : Whh[(size_t)g*Hh + (j - 2*Hh)];
  Wp[i] = f2bf(v);
}

__global__ void k_count(const int* __restrict__ dst, int* __restrict__ counts){
  int e = blockIdx.x*256 + threadIdx.x;
  if (e < Ee) atomicAdd(&counts[dst[e]], 1);
}

__global__ void k_dinv(const int* __restrict__ counts, float* __restrict__ dinv){
  int n = blockIdx.x*256 + threadIdx.x;
  if (n < Nn) dinv[n] = rsqrtf((float)(counts[n] + 1));
}

// ---------------- hierarchical scan (3 phases) ----------------
// phase 1: per-block (1024-elem chunk) sum -> partial[blockIdx]
__global__ void k_scan1(const int* __restrict__ counts, int* __restrict__ partial){
  __shared__ int red[256];
  int t = threadIdx.x;
  int base = blockIdx.x*SCHUNK + t*4;
  int s = 0;
  if (base + 3 < Nn){ int4 v = *reinterpret_cast<const int4*>(counts + base); s = v.x+v.y+v.z+v.w; }
  else { for (int i=0;i<4;++i) if (base+i<Nn) s += counts[base+i]; }
  red[t] = s; __syncthreads();
  for (int st=128; st>0; st>>=1){ if (t<st) red[t]+=red[t+st]; __syncthreads(); }
  if (t==0) partial[blockIdx.x] = red[0];
}

// phase 2: single block exclusive-scan of partial[0..n)
__global__ void k_scan2(int* __restrict__ partial, int n){
  __shared__ int buf[128];
  int t = threadIdx.x;
  int v = (t < n) ? partial[t] : 0;
  buf[t] = v; __syncthreads();
  for (int off=1; off<128; off<<=1){
    int tv = (t>=off) ? buf[t-off] : 0;
    __syncthreads();
    buf[t] += tv;
    __syncthreads();
  }
  if (t < n) partial[t] = buf[t] - v;   // exclusive
}

// phase 3: per-block local scan + base -> offs; last thread writes offs[Nn]
__global__ void k_scan3(const int* __restrict__ counts, const int* __restrict__ partial,
                        int* __restrict__ offs){
  __shared__ int red[256];
  int t = threadIdx.x;
  int base = blockIdx.x*SCHUNK + t*4;
  int c0=0,c1=0,c2=0,c3=0;
  if (base + 3 < Nn){ int4 v = *reinterpret_cast<const int4*>(counts + base); c0=v.x;c1=v.y;c2=v.z;c3=v.w; }
  else { if (base<Nn) c0=counts[base]; if (base+1<Nn) c1=counts[base+1];
         if (base+2<Nn) c2=counts[base+2]; if (base+3<Nn) c3=counts[base+3]; }
  int s = c0+c1+c2+c3;
  red[t] = s; __syncthreads();
  for (int off=1; off<256; off<<=1){
    int tv = (t>=off) ? red[t-off] : 0;
    __syncthreads();
    red[t] += tv;
    __syncthreads();
  }
  int run = partial[blockIdx.x] + red[t] - s;   // exclusive base for this thread
  if (base   < Nn) offs[base]   = run; run += c0;
  if (base+1 < Nn) offs[base+1] = run; run += c1;
  if (base+2 < Nn) offs[base+2] = run; run += c2;
  if (base+3 < Nn) offs[base+3] = run; run += c3;
  if (blockIdx.x == gridDim.x-1 && t == 255) offs[Nn] = partial[blockIdx.x] + red[255];
}

__global__ void k_copyi(const int* __restrict__ a, int* __restrict__ b, int n){
  int i = blockIdx.x*256 + threadIdx.x;
  if (i < n) b[i] = a[i];
}

__global__ void k_fill(const int* __restrict__ ei, const float* __restrict__ dinv,
                       int* __restrict__ fptr, int* __restrict__ srcs, float* __restrict__ norms){
  int e = blockIdx.x*256 + threadIdx.x;
  if (e >= Ee) return;
  int s = ei[e], d = ei[Ee + e];
  int pos = atomicAdd(&fptr[d], 1);
  srcs[pos]  = s;
  norms[pos] = dinv[s]*dinv[d];
}

__global__ void k_boffs(const int* __restrict__ batch, int* __restrict__ boffs){
  int b = blockIdx.x*256 + threadIdx.x;
  if (b > Bb) return;
  int lo = 0, hi = Nn;
  while (lo < hi){ int mid = (lo+hi)>>1; if (batch[mid] < b) lo = mid+1; else hi = mid; }
  boffs[b] = lo;
}

// ---------------- layer 0: vocab histogram (wave per node) ----------------
__global__ void k_hist(const int* __restrict__ sto_x, const int* __restrict__ offs,
                       const int* __restrict__ srcs, const float* __restrict__ norms,
                       const float* __restrict__ dinv, unsigned short* __restrict__ Vb){
  __shared__ float hist[4][KV];
  int wid = threadIdx.x >> 6, lane = threadIdx.x & 63;
  int n = blockIdx.x*4 + wid;
  hist[wid][lane] = 0.f; hist[wid][lane+64] = 0.f;
  __syncthreads();
  int s = offs[n], e = offs[n+1];
  for (int k = s + lane; k < e; k += 64){
    int r2 = sto_x[srcs[k]]; r2 = (r2 == 0) ? (Vv-1) : r2-1;
    atomicAdd(&hist[wid][r2], norms[k]);
  }
  if (lane == 0){
    int r0 = sto_x[n]; r0 = (r0 == 0) ? (Vv-1) : r0-1;
    float dn = dinv[n];
    atomicAdd(&hist[wid][r0], dn*dn);
  }
  __syncthreads();
  unsigned int p = ((unsigned int)f2bf(hist[wid][2*lane+1]) << 16) | f2bf(hist[wid][2*lane]);
  ((unsigned int*)Vb)[(size_t)n*(KV/2) + lane] = p;
}

// ---------------- GCN aggregate (wave per node, uint2 lanes, 4-edge unroll) ----------------
__global__ void k_agg(const unsigned short* __restrict__ Xb, const int* __restrict__ offs,
                      const int* __restrict__ srcs, const float* __restrict__ norms,
                      const float* __restrict__ dinv, unsigned short* __restrict__ T){
  int wid = threadIdx.x >> 6, lane = threadIdx.x & 63;
  int n = blockIdx.x*4 + wid;
  const uint2* Xv = (const uint2*)Xb;
  uint2 v = Xv[(size_t)n*64 + lane];
  float dn = dinv[n]; float s2 = dn*dn;
  float a0 = bf2f(v.x)*s2, a1 = bf2f(v.x>>16)*s2;
  float a2 = bf2f(v.y)*s2, a3 = bf2f(v.y>>16)*s2;
  int s = offs[n], e = offs[n+1];
  int k = s;
  for (; k + 3 < e; k += 4){
    int s0 = srcs[k], s1 = srcs[k+1], s2i = srcs[k+2], s3 = srcs[k+3];
    float n0 = norms[k], n1 = norms[k+1], n2 = norms[k+2], n3 = norms[k+3];
    uint2 g0 = Xv[(size_t)s0*64 + lane];
    uint2 g1 = Xv[(size_t)s1*64 + lane];
    uint2 g2 = Xv[(size_t)s2i*64 + lane];
    uint2 g3 = Xv[(size_t)s3*64 + lane];
    a0 += bf2f(g0.x)*n0; a1 += bf2f(g0.x>>16)*n0; a2 += bf2f(g0.y)*n0; a3 += bf2f(g0.y>>16)*n0;
    a0 += bf2f(g1.x)*n1; a1 += bf2f(g1.x>>16)*n1; a2 += bf2f(g1.y)*n1; a3 += bf2f(g1.y>>16)*n1;
    a0 += bf2f(g2.x)*n2; a1 += bf2f(g2.x>>16)*n2; a2 += bf2f(g2.y)*n2; a3 += bf2f(g2.y>>16)*n2;
    a0 += bf2f(g3.x)*n3; a1 += bf2f(g3.x>>16)*n3; a2 += bf2f(g3.y)*n3; a3 += bf2f(g3.y>>16)*n3;
  }
  for (; k < e; ++k){
    uint2 g0 = Xv[(size_t)srcs[k]*64 + lane];
    float n0 = norms[k];
    a0 += bf2f(g0.x)*n0; a1 += bf2f(g0.x>>16)*n0;
    a2 += bf2f(g0.y)*n0; a3 += bf2f(g0.y>>16)*n0;
  }
  uint2 o;
  o.x = (unsigned int)f2bf(a0) | ((unsigned int)f2bf(a1) << 16);
  o.y = (unsigned int)f2bf(a2) | ((unsigned int)f2bf(a3) << 16);
  ((uint2*)T)[(size_t)n*64 + lane] = o;
}

// ---------------- bf16 MFMA NT GEMM, 128x128 tile ----------------
__global__ __launch_bounds__(256) void k_gemm_bf16(
    const unsigned short* __restrict__ A, int lda,
    const unsigned short* __restrict__ Bt,
    const float* __restrict__ bias, const float* __restrict__ rowscale,
    const float* __restrict__ addf,
    float* __restrict__ Cf, unsigned short* __restrict__ Cb,
    int M, int K, int Nc, int relu)
{
  __shared__ unsigned short Al[128][40];
  __shared__ unsigned short Bl[128][40];
  int tid = threadIdx.x;
  int w = tid >> 6, lane = tid & 63;
  int wr = (w >> 1)*64, wc = (w & 1)*64;
  int l16 = lane & 15, kh = lane >> 4;
  int rbase = blockIdx.y*128, cbase = blockIdx.x*128;
  int sr = tid >> 2, sb = tid & 3;

  f32x4 acc[4][4] = {};

  for (int k0 = 0; k0 < K; k0 += 32){
    int kk = k0 + sb*8;
    uint4 a0 = make_uint4(0,0,0,0), a1 = make_uint4(0,0,0,0);
    int ar0 = rbase + sr, ar1 = rbase + sr + 64;
    if (ar0 < M) a0 = *reinterpret_cast<const uint4*>(A + (size_t)ar0*lda + kk);
    if (ar1 < M) a1 = *reinterpret_cast<const uint4*>(A + (size_t)ar1*lda + kk);
    uint4 b0 = *reinterpret_cast<const uint4*>(Bt + (size_t)(cbase + sr)*K + kk);
    uint4 b1 = *reinterpret_cast<const uint4*>(Bt + (size_t)(cbase + sr + 64)*K + kk);
    __syncthreads();
    *reinterpret_cast<uint4*>(&Al[sr][sb*8])    = a0;
    *reinterpret_cast<uint4*>(&Al[sr+64][sb*8]) = a1;
    *reinterpret_cast<uint4*>(&Bl[sr][sb*8])    = b0;
    *reinterpret_cast<uint4*>(&Bl[sr+64][sb*8]) = b1;
    __syncthreads();

    short8 af[4], bfv[4];
    #pragma unroll
    for (int m = 0; m < 4; ++m) af[m] = *reinterpret_cast<const short8*>(&Al[wr + m*16 + l16][kh*8]);
    #pragma unroll
    for (int n2 = 0; n2 < 4; ++n2) bfv[n2] = *reinterpret_cast<const short8*>(&Bl[wc + n2*16 + l16][kh*8]);
    #pragma unroll
    for (int m = 0; m < 4; ++m)
      #pragma unroll
      for (int n2 = 0; n2 < 4; ++n2)
        acc[m][n2] = __builtin_amdgcn_mfma_f32_16x16x32_bf16(af[m], bfv[n2], acc[m][n2], 0, 0, 0);
  }

  #pragma unroll
  for (int n2 = 0; n2 < 4; ++n2){
    int col = cbase + wc + n2*16 + l16;
    float bv = bias ? bias[col] : 0.f;
    #pragma unroll
    for (int m = 0; m < 4; ++m){
      #pragma unroll
      for (int i = 0; i < 4; ++i){
        int row = rbase + wr + m*16 + kh*4 + i;
        if (row >= M) continue;
        float v = acc[m][n2][i] + bv;
        if (addf) v += addf[(size_t)row*Nc + col];
        if (rowscale) v *= rowscale[row];
        if (relu) v = fmaxf(v, 0.f);
        if (Cf) Cf[(size_t)row*Nc + col] = v;
        if (Cb) Cb[(size_t)row*Nc + col] = f2bf(v);
      }
    }
  }
}

// ---------------- tiled fp32 NT GEMM (small GEMMs) ----------------
__global__ __launch_bounds__(256) void k_gemm_nt(
    const float* __restrict__ A, const float* __restrict__ Bt,
    const float* __restrict__ bias, const float* __restrict__ Dadd,
    float* __restrict__ C, int M, int K, int Nc, int accum, int act)
{
  __shared__ float As[64][20];
  __shared__ float Bs[64][20];
  int tid = threadIdx.x;
  int rbase = blockIdx.y*64, cbase = blockIdx.x*64;
  int ty = tid>>4, tx = tid&15;
  int lr = tid>>2, lq = tid&3;
  float acc[4][4] = {};
  for (int k0 = 0; k0 < K; k0 += 16){
    float4 av = make_float4(0,0,0,0), bv = make_float4(0,0,0,0);
    int kk = k0 + lq*4;
    int ar = rbase + lr;
    if (ar < M && kk < K){
      if (kk + 3 < K) av = *reinterpret_cast<const float4*>(A + (size_t)ar*K + kk);
      else { float t0[4] = {0,0,0,0}; for (int i=0; i<4 && kk+i<K; ++i) t0[i] = A[(size_t)ar*K + kk + i];
             av = make_float4(t0[0],t0[1],t0[2],t0[3]); }
    }
    int br = cbase + lr;
    if (br < Nc && kk < K){
      if (kk + 3 < K) bv = *reinterpret_cast<const float4*>(Bt + (size_t)br*K + kk);
      else { float t0[4] = {0,0,0,0}; for (int i=0; i<4 && kk+i<K; ++i) t0[i] = Bt[(size_t)br*K + kk + i];
             bv = make_float4(t0[0],t0[1],t0[2],t0[3]); }
    }
    __syncthreads();
    *reinterpret_cast<float4*>(&As[lr][lq*4]) = av;
    *reinterpret_cast<float4*>(&Bs[lr][lq*4]) = bv;
    __syncthreads();
    #pragma unroll
    for (int kc = 0; kc < 16; kc += 4){
      float4 a4[4], b4[4];
      #pragma unroll
      for (int i=0;i<4;++i) a4[i] = *reinterpret_cast<float4*>(&As[ty*4+i][kc]);
      #pragma unroll
      for (int j=0;j<4;++j) b4[j] = *reinterpret_cast<float4*>(&Bs[tx*4+j][kc]);
      #pragma unroll
      for (int i=0;i<4;++i)
        #pragma unroll
        for (int j=0;j<4;++j)
          acc[i][j] += a4[i].x*b4[j].x + a4[i].y*b4[j].y + a4[i].z*b4[j].z + a4[i].w*b4[j].w;
    }
  }
  #pragma unroll
  for (int i=0;i<4;++i){
    int r = rbase + ty*4 + i;
    if (r >= M) continue;
    #pragma unroll
    for (int j=0;j<4;++j){
      int cc = cbase + tx*4 + j;
      if (cc >= Nc) continue;
      float v = acc[i][j];
      if (accum) v += C[(size_t)r*Nc + cc];
      if (bias)  v += bias[cc];
      if (Dadd)  v += Dadd[(size_t)r*Nc + cc];
      if (act == 1) v = (v > 0.f) ? v : 0.01f*v;
      C[(size_t)r*Nc + cc] = v;
    }
  }
}

// ---------------- pooling / LSTM / head ----------------
__global__ void k_sto(const unsigned short* __restrict__ wxb, const int* __restrict__ boffs,
                      float* __restrict__ sto){
  int wid = threadIdx.x >> 6, lane = threadIdx.x & 63;
  int g = blockIdx.x*4 + wid;
  if (g >= Bb) return;
  const uint2* Xv = (const uint2*)wxb;
  int s = boffs[g], e = boffs[g+1];
  float a0=0.f, a1=0.f, a2=0.f, a3=0.f;
  for (int n=s; n<e; ++n){
    uint2 v = Xv[(size_t)n*64 + lane];
    a0 += bf2f(v.x); a1 += bf2f(v.x>>16);
    a2 += bf2f(v.y); a3 += bf2f(v.y>>16);
  }
  ((float4*)sto)[(size_t)g*64 + lane] = make_float4(a0,a1,a2,a3);
}

__global__ void k_bsum(const float* __restrict__ bih, const float* __restrict__ bhh,
                       float* __restrict__ bsum){
  int g = blockIdx.x*256 + threadIdx.x;
  if (g < 4*Hh) bsum[g] = bih[g] + bhh[g];
}

__global__ void k_lstm(const float* __restrict__ gates, float* __restrict__ cbuf,
                       float* __restrict__ hbuf, unsigned short* __restrict__ qh){
  int idx = blockIdx.x*256 + threadIdx.x;
  if (idx >= Bb*Hh) return;
  int b = idx >> 8, ch = idx & 255;
  const float* g = gates + (size_t)b*4*Hh;
  float ig = sigf(g[ch]);
  float fg = sigf(g[Hh + ch]);
  float gg = tanhf(g[2*Hh + ch]);
  float og = sigf(g[3*Hh + ch]);
  float cn = fg*cbuf[idx] + ig*gg;
  float hn = og*tanhf(cn);
  cbuf[idx] = cn; hbuf[idx] = hn;
  unsigned short hb = f2bf(hn);
  qh[(size_t)b*3*Hh + ch] = hb;
  qh[(size_t)b*3*Hh + 2*Hh + ch] = hb;
}

__global__ void k_e(const unsigned short* __restrict__ wxb, const float* __restrict__ hbuf,
                    const int* __restrict__ batch, float* __restrict__ ebuf){
  int node = blockIdx.x*4 + (threadIdx.x >> 6);
  int lane = threadIdx.x & 63;
  int b = batch[node];
  uint2 wv = ((const uint2*)wxb)[(size_t)node*64 + lane];
  float4 hv = ((const float4*)hbuf)[(size_t)b*64 + lane];
  float v = bf2f(wv.x)*hv.x + bf2f(wv.x>>16)*hv.y + bf2f(wv.y)*hv.z + bf2f(wv.y>>16)*hv.w;
  for (int off=32; off; off>>=1) v += __shfl_down(v, off, 64);
  if (lane == 0) ebuf[node] = v;
}

__global__ void k_attn(const float* __restrict__ ebuf, const unsigned short* __restrict__ wxb,
                       const int* __restrict__ boffs, unsigned short* __restrict__ qh){
  int wid = threadIdx.x >> 6, lane = threadIdx.x & 63;
  int g = blockIdx.x*4 + wid;
  if (g >= Bb) return;
  const uint2* Xv = (const uint2*)wxb;
  int s = boffs[g], e = boffs[g+1];
  float m = -INFINITY;
  for (int n=s+lane; n<e; n+=64) m = fmaxf(m, ebuf[n]);
  #pragma unroll
  for (int mask=32; mask; mask>>=1) m = fmaxf(m, __shfl_xor(m, mask, 64));
  float a0=0.f, a1=0.f, a2=0.f, a3=0.f, sum=0.f;
  for (int n=s; n<e; ++n){
    float p = expf(ebuf[n]-m);
    sum += p;
    uint2 v = Xv[(size_t)n*64 + lane];
    a0 += p*bf2f(v.x); a1 += p*bf2f(v.x>>16);
    a2 += p*bf2f(v.y); a3 += p*bf2f(v.y>>16);
  }
  float inv = 1.f/(sum + 1e-16f);
  a0 *= inv; a1 *= inv; a2 *= inv; a3 *= inv;
  uint2 o;
  o.x = (unsigned int)f2bf(a0) | ((unsigned int)f2bf(a1) << 16);
  o.y = (unsigned int)f2bf(a2) | ((unsigned int)f2bf(a3) << 16);
  ((uint2*)(qh + (size_t)g*3*Hh + Hh))[lane] = o;
}

__global__ void k_norm(float* __restrict__ mean){
  __shared__ float red[256];
  int b = blockIdx.x, tid = threadIdx.x;
  float v = mean[(size_t)b*Hh + tid];
  red[tid] = v*v; __syncthreads();
  for (int st=128; st>0; st>>=1){ if (tid<st) red[tid] += red[tid+st]; __syncthreads(); }
  float nrm = fmaxf(sqrtf(red[0]), 1e-12f);
  mean[(size_t)b*Hh + tid] = v/nrm;
}

__global__ void k_out(const float* __restrict__ y1, const float* __restrict__ p2W,
                      const float* __restrict__ p2b, float* __restrict__ out){
  __shared__ float red[128];
  int b = blockIdx.x, tid = threadIdx.x;
  float v = y1[(size_t)b*128 + tid]*p2W[tid];
  red[tid] = v; __syncthreads();
  for (int st=64; st>0; st>>=1){ if (tid<st) red[tid] += red[tid+st]; __syncthreads(); }
  if (tid == 0) out[b] = red[0] + p2b[0];
}

// ---------------- launch ----------------
extern "C" void kernel_launch(void* const* d_in, const int* in_sizes, int n_in,
                              void* d_out, int out_size, void* d_ws, size_t ws_size,
                              hipStream_t stream) {
  const float* weight   = (const float*)d_in[0];
  const int*   sto_x    = (const int*)  d_in[1];
  const int*   ei       = (const int*)  d_in[2];
  const float* sto_w    = (const float*)d_in[3];
  const int*   batch    = (const int*)  d_in[4];
  const float* gW0 = (const float*)d_in[5];   const float* gb0 = (const float*)d_in[6];
  const float* gW1 = (const float*)d_in[7];   const float* gb1 = (const float*)d_in[8];
  const float* gW2 = (const float*)d_in[9];   const float* gb2 = (const float*)d_in[10];
  const float* Wih = (const float*)d_in[11];  const float* Whh = (const float*)d_in[12];
  const float* bih = (const float*)d_in[13];  const float* bhh = (const float*)d_in[14];
  const float* mW  = (const float*)d_in[15];  const float* mb  = (const float*)d_in[16];
  const float* p0W = (const float*)d_in[17];  const float* p0b = (const float*)d_in[18];
  const float* p1W = (const float*)d_in[19];  const float* p1b = (const float*)d_in[20];
  const float* p2W = (const float*)d_in[21];  const float* p2b = (const float*)d_in[22];
  float* out = (float*)d_out;

  // workspace carve (256B aligned)
  char* w = (char*)d_ws;
  auto alloc = [&](size_t bytes)->char*{ char* p = w; w += (bytes + 255) & ~size_t(255); return p; };
  unsigned short* Xb = (unsigned short*)alloc((size_t)Nn*Hh*2);
  unsigned short* Tb = (unsigned short*)alloc((size_t)Nn*Hh*2);
  unsigned short* Vb = (unsigned short*)alloc((size_t)Nn*KV*2);
  float* WG0   = (float*)alloc((size_t)Vv*Hh*4);
  unsigned short* WG0tb = (unsigned short*)alloc((size_t)Hh*KV*2);
  float* gW0t  = (float*)alloc((size_t)Hh*DIN*4);
  unsigned short* gW1tb = (unsigned short*)alloc((size_t)Hh*Hh*2);
  unsigned short* gW2tb = (unsigned short*)alloc((size_t)Hh*Hh*2);
  unsigned short* Wpb   = (unsigned short*)alloc((size_t)4*Hh*3*Hh*2);
  unsigned short* mWb   = (unsigned short*)alloc((size_t)Hh*2*Hh*2);
  int*   counts= (int*)  alloc((size_t)Nn*4);
  int*   offs  = (int*)  alloc((size_t)(Nn+1)*4);
  int*   fptr  = (int*)  alloc((size_t)Nn*4);
  int*   spart = (int*)  alloc((size_t)NSCAN*4);
  float* dinv  = (float*)alloc((size_t)Nn*4);
  int*   srcs  = (int*)  alloc((size_t)Ee*4);
  float* norms = (float*)alloc((size_t)Ee*4);
  int*   boffs = (int*)  alloc((size_t)(Bb+1)*4);
  float* ebuf  = (float*)alloc((size_t)Nn*4);
  float* sto   = (float*)alloc((size_t)Bb*Hh*4);
  float* hbuf  = (float*)alloc((size_t)Bb*Hh*4);
  float* cbuf  = (float*)alloc((size_t)Bb*Hh*4);
  unsigned short* qh = (unsigned short*)alloc((size_t)Bb*3*Hh*2);
  float* gates = (float*)alloc((size_t)Bb*4*Hh*4);
  float* bsum  = (float*)alloc((size_t)4*Hh*4);
  float* meanb = (float*)alloc((size_t)Bb*Hh*4);
  float* y0    = (float*)alloc((size_t)Bb*128*4);
  float* y1    = (float*)alloc((size_t)Bb*128*4);

  auto gemm = [&](const float* A, const float* Bt, const float* bias, const float* Dadd,
                  float* C, int M, int K, int Nc, int accum, int act){
    dim3 g((Nc+63)/64, (M+63)/64);
    k_gemm_nt<<<g, 256, 0, stream>>>(A, Bt, bias, Dadd, C, M, K, Nc, accum, act);
  };
  auto gemmb = [&](const unsigned short* A, int lda, const unsigned short* Bt,
                   const float* bias, const float* rowscale, const float* addf,
                   float* Cf, unsigned short* Cb, int M, int K, int Nc, int relu){
    dim3 g(Nc/128, (M+127)/128);
    k_gemm_bf16<<<g, 256, 0, stream>>>(A, lda, Bt, bias, rowscale, addf, Cf, Cb, M, K, Nc, relu);
  };

  // per-launch state init (deterministic every call)
  hipMemsetAsync(counts, 0, (size_t)Nn*4, stream);
  hipMemsetAsync(cbuf,  0, (size_t)Bb*Hh*4, stream);
  hipMemsetAsync(qh,    0, (size_t)Bb*3*Hh*2, stream);

  // weight prep
  k_transpose<<<(DIN*Hh+255)/256, 256, 0, stream>>>(gW0, gW0t, DIN, Hh);
  k_transpose_b<<<(Hh*Hh+255)/256, 256, 0, stream>>>(gW1, gW1tb, Hh, Hh);
  k_transpose_b<<<(Hh*Hh+255)/256, 256, 0, stream>>>(gW2, gW2tb, Hh, Hh);
  k_packW<<<(4*Hh*3*Hh+255)/256, 256, 0, stream>>>(Wih, Whh, Wpb);
  k_castb<<<(Hh*2*Hh+255)/256, 256, 0, stream>>>(mW, mWb, Hh*2*Hh);

  // graph structure (hierarchical scan)
  k_count<<<(Ee+255)/256, 256, 0, stream>>>(ei + Ee, counts);
  k_dinv<<<(Nn+255)/256, 256, 0, stream>>>(counts, dinv);
  k_scan1<<<NSCAN, 256, 0, stream>>>(counts, spart);
  k_scan2<<<1, 128, 0, stream>>>(spart, NSCAN);
  k_scan3<<<NSCAN, 256, 0, stream>>>(counts, spart, offs);
  k_copyi<<<(Nn+255)/256, 256, 0, stream>>>(offs, fptr, Nn);
  k_fill<<<(Ee+255)/256, 256, 0, stream>>>(ei, dinv, fptr, srcs, norms);
  k_boffs<<<(Bb+256)/256, 256, 0, stream>>>(batch, boffs);

  // layer 0: WG0 = weight@gW0, vocab histogram, MFMA GEMM with bias+relu
  gemm(weight, gW0t, nullptr, nullptr, WG0, Vv, DIN, Hh, 0, 0);
  k_wg0t<<<(Hh*KV+255)/256, 256, 0, stream>>>(WG0, WG0tb);
  k_hist<<<Nn/4, 256, 0, stream>>>(sto_x, offs, srcs, norms, dinv, Vb);
  gemmb(Vb, KV, WG0tb, gb0, nullptr, nullptr, nullptr, Xb, Nn, KV, Hh, 1);

  // layers 1,2: aggregate-first, GEMM with fused epilogue
  k_agg<<<Nn/4, 256, 0, stream>>>(Xb, offs, srcs, norms, dinv, Tb);
  gemmb(Tb, Hh, gW1tb, gb1, nullptr, nullptr, nullptr, Xb, Nn, Hh, Hh, 1);
  k_agg<<<Nn/4, 256, 0, stream>>>(Xb, offs, srcs, norms, dinv, Tb);
  gemmb(Tb, Hh, gW2tb, gb2, sto_w, nullptr, nullptr, Xb, Nn, Hh, Hh, 0);  // Xb = wx

  // graph sums
  k_sto<<<Bb/4, 256, 0, stream>>>(Xb, boffs, sto);
  k_bsum<<<(4*Hh+255)/256, 256, 0, stream>>>(bih, bhh, bsum);

  // Set2Set (2 steps)
  for (int t = 0; t < 2; ++t){
    gemmb(qh, 3*Hh, Wpb, bsum, nullptr, nullptr, gates, nullptr, Bb, 3*Hh, 4*Hh, 0);
    k_lstm<<<(Bb*Hh+255)/256, 256, 0, stream>>>(gates, cbuf, hbuf, qh);
    k_e<<<Nn/4, 256, 0, stream>>>(Xb, hbuf, batch, ebuf);
    k_attn<<<Bb/4, 256, 0, stream>>>(ebuf, Xb, boffs, qh);
  }

  // head
  gemmb(qh, 3*Hh, mWb, mb, nullptr, sto, meanb, nullptr, Bb, 2*Hh, Hh, 0);
  k_norm<<<Bb, Hh, 0, stream>>>(meanb);
  gemm(meanb, p0W, p0b, nullptr, y0, Bb, Hh, 128, 0, 1);
  gemm(y0, p1W, p1b, nullptr, y1, Bb, 128, 128, 0, 1);
  k_out<<<Bb, 128, 0, stream>>>(y1, p2W, p2b, out);
}